// Round 1
// baseline (265.745 us; speedup 1.0000x reference)
//
#include <hip/hip_runtime.h>
#include <cstdint>
#include <cstddef>

typedef __bf16 bf16;
typedef __attribute__((ext_vector_type(8))) __bf16 bf16x8;
typedef __attribute__((ext_vector_type(4))) __bf16 bf16x4;
typedef __attribute__((ext_vector_type(2))) __bf16 bf16x2;
typedef __attribute__((ext_vector_type(4))) float f32x4;
typedef unsigned int u32;

#define D_MODEL 2048
#define QSCALE      0.17677669529663687f                      // 1/sqrt(32)
#define QSCALE_L2E  (0.17677669529663687f * 1.4426950408889634f)  // fold log2(e): exp(x)=exp2(x*l2e)

// async global->LDS, 16B per lane. LDS dest is wave-uniform base + lane*16.
__device__ inline void async_load16(const void* gp, void* lp) {
  __builtin_amdgcn_global_load_lds(
      (const __attribute__((address_space(1))) u32*)gp,
      (__attribute__((address_space(3))) u32*)lp, 16, 0, 0);
}

// ---------------------------------------------------------------------------
// Convert fp32 -> bf16, 8 elements/thread (exact-multiple grids only).
// ---------------------------------------------------------------------------
__global__ __launch_bounds__(256) void cvt_k(const float* __restrict__ x,
                                             bf16* __restrict__ xb) {
  const int i = (blockIdx.x * 256 + threadIdx.x) * 8;
  float4 a = *(const float4*)(x + i);
  float4 b = *(const float4*)(x + i + 4);
  bf16x8 o;
  o[0] = (bf16)a.x; o[1] = (bf16)a.y; o[2] = (bf16)a.z; o[3] = (bf16)a.w;
  o[4] = (bf16)b.x; o[5] = (bf16)b.y; o[6] = (bf16)b.z; o[7] = (bf16)b.w;
  *(bf16x8*)(xb + i) = o;
}

// ---------------------------------------------------------------------------
// Fold 1: EffT[(mat*16+h)*32 + r][d] = sum_dh W[h*128+dh][d] * Wdown[dh][r]
// ---------------------------------------------------------------------------
__global__ __launch_bounds__(256) void fold_qkv_k(
    const float* __restrict__ Wq, const float* __restrict__ Wk,
    const float* __restrict__ Wv, const float* __restrict__ Wdown,
    bf16* __restrict__ EffT) {
  __shared__ float wd[128][32];
  const int t = threadIdx.x;
  for (int i = t; i < 128 * 32; i += 256)
    ((float*)wd)[i] = Wdown[i];
  __syncthreads();
  const int mh = blockIdx.x;                         // mat*16 + h
  const float* W = (mh < 16) ? Wq : ((mh < 32) ? Wk : Wv);
  const int hrow = (mh & 15) * 128;
  const int d = blockIdx.y * 128 + (t & 127);
  const int rh = (t >> 7) * 16;                      // wave-uniform: 0 or 16
  float acc[16];
#pragma unroll
  for (int j = 0; j < 16; ++j) acc[j] = 0.f;
#pragma unroll 4
  for (int k = 0; k < 128; ++k) {
    float w = W[(size_t)(hrow + k) * D_MODEL + d];
    const float* wr = &wd[k][rh];                    // broadcast ds reads
#pragma unroll
    for (int j = 0; j < 16; ++j) acc[j] += w * wr[j];
  }
  bf16* outp = EffT + (size_t)(mh * 32 + rh) * D_MODEL + d;
#pragma unroll
  for (int j = 0; j < 16; ++j) outp[(size_t)j * D_MODEL] = (bf16)acc[j];
}

// ---------------------------------------------------------------------------
// Fold 2 via MFMA: for each h, C_h[2048 d][32 r] = Wo_h[2048x128] @ Wup^T.
// ---------------------------------------------------------------------------
__global__ __launch_bounds__(256) void fold_o_k(
    const bf16* __restrict__ Wob, const float* __restrict__ Wup,
    bf16* __restrict__ WoEffT) {
  __shared__ __align__(16) bf16 As_[128 * 128];   // 32 KB
  __shared__ __align__(16) bf16 Bs_[32 * 128];    //  8 KB
  const int t = threadIdx.x, wave = t >> 6, lane = t & 63;
  const int quad = lane >> 4, lc = lane & 15;
  const int d0 = blockIdx.x * 128, h = blockIdx.y;
#pragma unroll
  for (int a = 0; a < 8; ++a) {
    int r0 = wave * 32 + a * 4;
    int row = r0 + (lane >> 4);
    int g = (lane & 15) ^ (row & 15);
    async_load16(Wob + (size_t)(d0 + row) * 2048 + h * 128 + g * 8,
                 As_ + r0 * 128);
  }
  {
    int row = t >> 3;                 // 0..31
    int c0 = (t & 7) * 2;             // chunk pair
    const float* src = Wup + row * 128 + c0 * 8;
    float4 f0 = ((const float4*)src)[0], f1 = ((const float4*)src)[1];
    float4 f2 = ((const float4*)src)[2], f3 = ((const float4*)src)[3];
    bf16x8 b0, b1;
    b0[0] = (bf16)f0.x; b0[1] = (bf16)f0.y; b0[2] = (bf16)f0.z; b0[3] = (bf16)f0.w;
    b0[4] = (bf16)f1.x; b0[5] = (bf16)f1.y; b0[6] = (bf16)f1.z; b0[7] = (bf16)f1.w;
    b1[0] = (bf16)f2.x; b1[1] = (bf16)f2.y; b1[2] = (bf16)f2.z; b1[3] = (bf16)f2.w;
    b1[4] = (bf16)f3.x; b1[5] = (bf16)f3.y; b1[6] = (bf16)f3.z; b1[7] = (bf16)f3.w;
    *(bf16x8*)(Bs_ + row * 128 + ((c0 ^ (row & 15)) * 8)) = b0;
    *(bf16x8*)(Bs_ + row * 128 + (((c0 + 1) ^ (row & 15)) * 8)) = b1;
  }
  __syncthreads();
  f32x4 acc[2][2] = {};
  const int wm = wave * 32;
#pragma unroll
  for (int kc = 0; kc < 4; ++kc) {
    bf16x8 af[2], bfr[2];
#pragma unroll
    for (int mi = 0; mi < 2; ++mi) {
      int m = wm + mi * 16 + lc;
      af[mi] = *(const bf16x8*)(As_ + m * 128 + (((kc * 4 + quad) ^ (m & 15)) * 8));
    }
#pragma unroll
    for (int ni = 0; ni < 2; ++ni) {
      int n = ni * 16 + lc;
      bfr[ni] = *(const bf16x8*)(Bs_ + n * 128 + (((kc * 4 + quad) ^ (n & 15)) * 8));
    }
#pragma unroll
    for (int mi = 0; mi < 2; ++mi)
#pragma unroll
      for (int ni = 0; ni < 2; ++ni)
        acc[mi][ni] = __builtin_amdgcn_mfma_f32_16x16x32_bf16(
            af[mi], bfr[ni], acc[mi][ni], 0, 0, 0);
  }
#pragma unroll
  for (int mi = 0; mi < 2; ++mi)
#pragma unroll
    for (int ni = 0; ni < 2; ++ni)
#pragma unroll
      for (int reg = 0; reg < 4; ++reg)
        WoEffT[(size_t)(d0 + wm + mi * 16 + quad * 4 + reg) * 512 + h * 32 +
               ni * 16 + lc] = (bf16)acc[mi][ni][reg];
}

// ---------------------------------------------------------------------------
// GEMM  C = A @ Bt^T.  A[M×K], Bt[N×K] bf16, fp32 accum. Tile 128×128, 4
// waves each 64×64 (4×4 frags), BK=64, double-buffered, one barrier/iter.
// 128B LDS rows (8 x16B slots), src-col swizzle g = slot ^ (row&7).
// EPI==1 (QKV producer):
//   mat 0 (Q): scaled by QSCALE*log2e (attn uses exp2).
//   mat 2 (V): stored TRANSPOSED per bh, tiled [16 kt][32 r][128 k] with
//              16B-chunk swizzle chunk' = chunk ^ (r&15) — exactly the linear
//              LDS image attn_k wants, so attn stages V via global_load_lds
//              with zero VALU work. mat is block-uniform (128-col tiles never
//              cross the 512-col mat boundary) -> no divergence.
// ---------------------------------------------------------------------------
template <int EPI>
__global__ __launch_bounds__(256) void gemm_bt_k(
    const bf16* __restrict__ A, const bf16* __restrict__ Bt,
    void* __restrict__ Cv, int M, int N, int K) {
  __shared__ __align__(16) bf16 As[2][128 * 64];   // 32 KB
  __shared__ __align__(16) bf16 Bs[2][128 * 64];   // 32 KB
  const int t = threadIdx.x, wave = t >> 6, lane = t & 63;
  const int quad = lane >> 4, lc = lane & 15;
  const size_t m0 = (size_t)blockIdx.x * 128;
  const size_t n0 = (size_t)blockIdx.y * 128;
  const int wm = (wave >> 1) * 64, wn = (wave & 1) * 64;
  const int sr = lane >> 3, ss = lane & 7;
  const bf16* Aga[4]; const bf16* Bga[4]; int Loff[4];
#pragma unroll
  for (int a = 0; a < 4; ++a) {
    int row = wave * 32 + a * 8 + sr;
    Aga[a] = A + (m0 + row) * (size_t)K + (ss ^ (row & 7)) * 8;
    Bga[a] = Bt + (n0 + row) * (size_t)K + (ss ^ (row & 7)) * 8;
    Loff[a] = (wave * 32 + a * 8) * 64;
  }
  f32x4 acc[4][4] = {};
  const int NIT = K >> 6;
#pragma unroll
  for (int a = 0; a < 4; ++a) {
    async_load16(Aga[a], &As[0][Loff[a]]);
    async_load16(Bga[a], &Bs[0][Loff[a]]);
  }
  __syncthreads();
  for (int it = 0; it < NIT; ++it) {
    const int cur = it & 1;
    if (it + 1 < NIT) {
      const int k0 = (it + 1) * 64;
#pragma unroll
      for (int a = 0; a < 4; ++a) {
        async_load16(Aga[a] + k0, &As[1 - cur][Loff[a]]);
        async_load16(Bga[a] + k0, &Bs[1 - cur][Loff[a]]);
      }
    }
    const bf16* Asb = As[cur];
    const bf16* Bsb = Bs[cur];
#pragma unroll
    for (int kc = 0; kc < 2; ++kc) {
      bf16x8 af[4], bfr[4];
#pragma unroll
      for (int mi = 0; mi < 4; ++mi) {
        int m = wm + mi * 16 + lc;
        af[mi] = *(const bf16x8*)(Asb + m * 64 + (((kc * 4 + quad) ^ (m & 7)) * 8));
      }
#pragma unroll
      for (int ni = 0; ni < 4; ++ni) {
        int n = wn + ni * 16 + lc;
        bfr[ni] = *(const bf16x8*)(Bsb + n * 64 + (((kc * 4 + quad) ^ (n & 7)) * 8));
      }
#pragma unroll
      for (int mi = 0; mi < 4; ++mi)
#pragma unroll
        for (int ni = 0; ni < 4; ++ni)
          acc[mi][ni] = __builtin_amdgcn_mfma_f32_16x16x32_bf16(
              af[mi], bfr[ni], acc[mi][ni], 0, 0, 0);
    }
    __syncthreads();
  }

  if (EPI == 0) {
    float* C = (float*)Cv;
#pragma unroll
    for (int mi = 0; mi < 4; ++mi)
#pragma unroll
      for (int ni = 0; ni < 4; ++ni) {
        size_t row = m0 + wm + mi * 16 + quad * 4;
        size_t col = n0 + wn + ni * 16 + lc;
#pragma unroll
        for (int reg = 0; reg < 4; ++reg)
          C[(row + reg) * (size_t)N + col] = acc[mi][ni][reg];
      }
  } else {
    bf16* C = (bf16*)Cv;
#pragma unroll
    for (int mi = 0; mi < 4; ++mi)
#pragma unroll
      for (int ni = 0; ni < 4; ++ni) {
        int n = (int)n0 + wn + ni * 16 + lc;
        int mat = n >> 9, hh = (n >> 5) & 15, r = n & 31;
        float sc = (mat == 0) ? QSCALE_L2E : 1.0f;
        int trow = (int)m0 + wm + mi * 16 + quad * 4;
#pragma unroll
        for (int reg = 0; reg < 4; ++reg) {
          int tr = trow + reg;
          int b = tr >> 11, tl = tr & 2047;
          size_t off;
          if (mat == 2) {
            int tile = tl >> 7, kin = tl & 127;
            off = ((size_t)(b * 16 + hh) * 3 + 2) * 65536 +
                  (size_t)tile * 4096 + r * 128 +
                  (((kin >> 3) ^ (r & 15)) << 3) + (kin & 7);
          } else {
            off = (((size_t)(b * 16 + hh) * 3 + mat) * 2048 + tl) * 32 + r;
          }
          C[off] = (bf16)(acc[mi][ni][reg] * sc);
        }
      }
  }
}

// ---------------------------------------------------------------------------
// Flash attention in rank space (no max-tracking). S computed TRANSPOSED:
// S^T = mfma(a=K_frag, b=Q_frag) so each lane's 4 acc regs are 4 consecutive
// k at fixed q, packing P into ONE ds_write_b64 per (u,tile).
// V arrives pre-transposed+tiled+swizzled from the producer -> staged straight
// into LDS via global_load_lds (no per-thread transpose, no LDS writes).
// Row sums via MFMA against a ones vector (lands in the same acc layout as O:
// os[reg] is exactly the row this lane stores -> no shuffles, and numerator/
// denominator use the same bf16-rounded P). exp2 with pre-folded log2e scale.
// grid (32 bh, 16 qb) = 512 blocks = exactly 2/CU.
// ---------------------------------------------------------------------------
__global__ __launch_bounds__(256) void attn_k(const bf16* __restrict__ QKVr,
                                              bf16* __restrict__ Yr) {
  const int bh = blockIdx.x, qb = blockIdx.y;
  const size_t base = (size_t)bh * 3 * 2048 * 32;
  const bf16* Q  = QKVr + base;
  const bf16* Kr = Q + 2048 * 32;
  const bf16* Vr = Kr + 2048 * 32;                 // [16 kt][32 r][128 k] swizzled
  __shared__ __align__(16) bf16 Ks[2][128 * 32];   // 16 KB
  __shared__ __align__(16) bf16 Vt[2][32 * 128];   // 16 KB
  __shared__ __align__(16) bf16 Ps[4 * 32 * 128];  // 32 KB
  const int t = threadIdx.x, wave = t >> 6, lane = t & 63;
  const int quad = lane >> 4, lc = lane & 15;
  const int qbase = qb * 128 + wave * 32;
  const bf16x8 qf0 = *(const bf16x8*)(Q + (size_t)(qbase + lc) * 32 + quad * 8);
  const bf16x8 qf1 = *(const bf16x8*)(Q + (size_t)(qbase + 16 + lc) * 32 + quad * 8);
  f32x4 o00 = {}, o01 = {}, o10 = {}, o11 = {};
  f32x4 os0 = {}, os1 = {};
  bf16x8 ones;
#pragma unroll
  for (int j = 0; j < 8; ++j) ones[j] = (bf16)1.0f;
  const int krow = wave * 16 + (lane >> 2);
  const bf16* Kg = Kr + (size_t)krow * 32 + ((lane & 3) ^ ((krow >> 1) & 3)) * 8;
  bf16* pw = Ps + wave * 32 * 128;

  // prologue: stage tile 0 (K rows + V^T image, both via async DMA)
  async_load16(Kg, &Ks[0][wave * 16 * 32]);
  async_load16(Kg + (size_t)64 * 32, &Ks[0][(64 + wave * 16) * 32]);
  async_load16(Vr + (wave * 2) * 512 + lane * 8, &Vt[0][(wave * 2) * 512]);
  async_load16(Vr + (wave * 2 + 1) * 512 + lane * 8, &Vt[0][(wave * 2 + 1) * 512]);
  __syncthreads();

  for (int it = 0; it < 16; ++it) {
    const int kt = it * 128, cur = it & 1;
    if (it < 15) {
      async_load16(Kg + (size_t)(kt + 128) * 32, &Ks[1 - cur][wave * 16 * 32]);
      async_load16(Kg + (size_t)(kt + 192) * 32, &Ks[1 - cur][(64 + wave * 16) * 32]);
      const bf16* vg = Vr + (size_t)(it + 1) * 4096;
      async_load16(vg + (wave * 2) * 512 + lane * 8, &Vt[1 - cur][(wave * 2) * 512]);
      async_load16(vg + (wave * 2 + 1) * 512 + lane * 8, &Vt[1 - cur][(wave * 2 + 1) * 512]);
    }
    const bf16* ksb = Ks[cur];
    // --- S^T = K Q^T per 16-key tile; exp2; pack; one b64 write per (u,tile) ---
#pragma unroll
    for (int ni = 0; ni < 8; ++ni) {
      int n = ni * 16 + lc;
      bf16x8 kf = *(const bf16x8*)(ksb + n * 32 + ((quad ^ ((n >> 1) & 3)) * 8));
      f32x4 z = {0.f, 0.f, 0.f, 0.f};
      __builtin_amdgcn_s_setprio(1);
      f32x4 s0 = __builtin_amdgcn_mfma_f32_16x16x32_bf16(kf, qf0, z, 0, 0, 0);
      f32x4 s1 = __builtin_amdgcn_mfma_f32_16x16x32_bf16(kf, qf1, z, 0, 0, 0);
      __builtin_amdgcn_s_setprio(0);
      bf16x4 p0, p1;
#pragma unroll
      for (int reg = 0; reg < 4; ++reg) {
        p0[reg] = (bf16)exp2f(s0[reg]);
        p1[reg] = (bf16)exp2f(s1[reg]);
      }
      int off = (((2 * ni + (quad >> 1)) ^ lc) * 8) + (quad & 1) * 4;
      *(bf16x4*)(pw + lc * 128 + off) = p0;
      *(bf16x4*)(pw + (16 + lc) * 128 + off) = p1;
    }
    // --- O += P V ; row-sums += P * ones (same acc layout as O) ---
    const bf16* vtb = Vt[cur];
    __builtin_amdgcn_s_setprio(1);
#pragma unroll
    for (int kc = 0; kc < 4; ++kc) {
      int co = ((kc * 4 + quad) ^ lc) * 8;
      bf16x8 pf0 = *(const bf16x8*)(pw + lc * 128 + co);
      bf16x8 pf1 = *(const bf16x8*)(pw + (16 + lc) * 128 + co);
      bf16x8 v0 = *(const bf16x8*)(vtb + lc * 128 + co);
      bf16x8 v1 = *(const bf16x8*)(vtb + (16 + lc) * 128 + co);
      o00 = __builtin_amdgcn_mfma_f32_16x16x32_bf16(pf0, v0, o00, 0, 0, 0);
      o01 = __builtin_amdgcn_mfma_f32_16x16x32_bf16(pf0, v1, o01, 0, 0, 0);
      o10 = __builtin_amdgcn_mfma_f32_16x16x32_bf16(pf1, v0, o10, 0, 0, 0);
      o11 = __builtin_amdgcn_mfma_f32_16x16x32_bf16(pf1, v1, o11, 0, 0, 0);
      os0 = __builtin_amdgcn_mfma_f32_16x16x32_bf16(pf0, ones, os0, 0, 0, 0);
      os1 = __builtin_amdgcn_mfma_f32_16x16x32_bf16(pf1, ones, os1, 0, 0, 0);
    }
    __builtin_amdgcn_s_setprio(0);
    __syncthreads();
  }
  // --- normalize & store: os[reg] is the sum for exactly this lane's row ---
  const int b = bh >> 4, h = bh & 15;
#pragma unroll
  for (int reg = 0; reg < 4; ++reg) {
    float i0 = 1.0f / os0[reg];
    float i1 = 1.0f / os1[reg];
    size_t r0 = (size_t)b * 2048 + qbase + quad * 4 + reg;
    size_t r1 = r0 + 16;
    Yr[r0 * 512 + h * 32 + lc]      = (bf16)(o00[reg] * i0);
    Yr[r0 * 512 + h * 32 + 16 + lc] = (bf16)(o01[reg] * i0);
    Yr[r1 * 512 + h * 32 + lc]      = (bf16)(o10[reg] * i1);
    Yr[r1 * 512 + h * 32 + 16 + lc] = (bf16)(o11[reg] * i1);
  }
}

// ---------------------------------------------------------------------------
extern "C" void kernel_launch(void* const* d_in, const int* in_sizes, int n_in,
                              void* d_out, int out_size, void* d_ws, size_t ws_size,
                              hipStream_t stream) {
  const float* x     = (const float*)d_in[0];
  const float* Wq    = (const float*)d_in[1];
  const float* Wk    = (const float*)d_in[2];
  const float* Wv    = (const float*)d_in[3];
  const float* Wo    = (const float*)d_in[4];
  const float* Wdown = (const float*)d_in[5];
  const float* Wup   = (const float*)d_in[6];
  float* out = (float*)d_out;

  char* ws = (char*)d_ws;
  bf16* EffT   = (bf16*)(ws);                 // [1536][2048]       6,291,456 B
  bf16* WoEffT = (bf16*)(ws + 6291456);       // [2048][512]        2,097,152 B
  bf16* QKVr   = (bf16*)(ws + 8388608);       // [32][3][2048][32] 12,582,912 B
  bf16* Wob    = (bf16*)(ws + 8388608);       // [2048][2048] — dead before QKVr written
  bf16* Yrb    = (bf16*)(ws + 20971520);      // [4096][512]        4,194,304 B
  bf16* xb     = (bf16*)(ws + 25165824);      // [4096][2048]      16,777,216 B

  cvt_k<<<dim3(4096), dim3(256), 0, stream>>>(x, xb);
  cvt_k<<<dim3(2048), dim3(256), 0, stream>>>(Wo, Wob);
  fold_qkv_k<<<dim3(48, 16), dim3(256), 0, stream>>>(Wq, Wk, Wv, Wdown, EffT);
  fold_o_k<<<dim3(16, 16), dim3(256), 0, stream>>>(Wob, Wup, WoEffT);
  gemm_bt_k<1><<<dim3(32, 12), dim3(256), 0, stream>>>(xb, EffT, QKVr,
                                                       4096, 1536, 2048);
  attn_k<<<dim3(32, 16), dim3(256), 0, stream>>>(QKVr, Yrb);
  gemm_bt_k<0><<<dim3(32, 16), dim3(256), 0, stream>>>(Yrb, WoEffT, out,
                                                       4096, 2048, 512);
}

// Round 2
// 248.682 us; speedup vs baseline: 1.0686x; 1.0686x over previous
//
#include <hip/hip_runtime.h>
#include <cstdint>
#include <cstddef>

typedef __bf16 bf16;
typedef __attribute__((ext_vector_type(8))) __bf16 bf16x8;
typedef __attribute__((ext_vector_type(4))) __bf16 bf16x4;
typedef __attribute__((ext_vector_type(2))) __bf16 bf16x2;
typedef __attribute__((ext_vector_type(4))) float f32x4;
typedef unsigned int u32;

#define D_MODEL 2048
#define QSCALE      0.17677669529663687f                      // 1/sqrt(32)
#define QSCALE_L2E  (0.17677669529663687f * 1.4426950408889634f)  // fold log2(e): exp(x)=exp2(x*l2e)

// async global->LDS, 16B per lane. LDS dest is wave-uniform base + lane*16.
__device__ inline void async_load16(const void* gp, void* lp) {
  __builtin_amdgcn_global_load_lds(
      (const __attribute__((address_space(1))) u32*)gp,
      (__attribute__((address_space(3))) u32*)lp, 16, 0, 0);
}

// Raw v_exp_f32 (2^x). Library exp2f takes the OCML accurate path (~10+ VALU
// instrs of range fixup); the builtin is a single transcendental op.
__device__ inline float fast_exp2(float x) {
#if __has_builtin(__builtin_amdgcn_exp2f)
  return __builtin_amdgcn_exp2f(x);
#else
  return __expf(x * 0.6931471805599453f);
#endif
}

// ---------------------------------------------------------------------------
// Convert fp32 -> bf16, 8 elements/thread (exact-multiple grids only).
// ---------------------------------------------------------------------------
__global__ __launch_bounds__(256) void cvt_k(const float* __restrict__ x,
                                             bf16* __restrict__ xb) {
  const int i = (blockIdx.x * 256 + threadIdx.x) * 8;
  float4 a = *(const float4*)(x + i);
  float4 b = *(const float4*)(x + i + 4);
  bf16x8 o;
  o[0] = (bf16)a.x; o[1] = (bf16)a.y; o[2] = (bf16)a.z; o[3] = (bf16)a.w;
  o[4] = (bf16)b.x; o[5] = (bf16)b.y; o[6] = (bf16)b.z; o[7] = (bf16)b.w;
  *(bf16x8*)(xb + i) = o;
}

// ---------------------------------------------------------------------------
// Fold 1: EffT[(mat*16+h)*32 + r][d] = sum_dh W[h*128+dh][d] * Wdown[dh][r]
// ---------------------------------------------------------------------------
__global__ __launch_bounds__(256) void fold_qkv_k(
    const float* __restrict__ Wq, const float* __restrict__ Wk,
    const float* __restrict__ Wv, const float* __restrict__ Wdown,
    bf16* __restrict__ EffT) {
  __shared__ float wd[128][32];
  const int t = threadIdx.x;
  for (int i = t; i < 128 * 32; i += 256)
    ((float*)wd)[i] = Wdown[i];
  __syncthreads();
  const int mh = blockIdx.x;                         // mat*16 + h
  const float* W = (mh < 16) ? Wq : ((mh < 32) ? Wk : Wv);
  const int hrow = (mh & 15) * 128;
  const int d = blockIdx.y * 128 + (t & 127);
  const int rh = (t >> 7) * 16;                      // wave-uniform: 0 or 16
  float acc[16];
#pragma unroll
  for (int j = 0; j < 16; ++j) acc[j] = 0.f;
#pragma unroll 4
  for (int k = 0; k < 128; ++k) {
    float w = W[(size_t)(hrow + k) * D_MODEL + d];
    const float* wr = &wd[k][rh];                    // broadcast ds reads
#pragma unroll
    for (int j = 0; j < 16; ++j) acc[j] += w * wr[j];
  }
  bf16* outp = EffT + (size_t)(mh * 32 + rh) * D_MODEL + d;
#pragma unroll
  for (int j = 0; j < 16; ++j) outp[(size_t)j * D_MODEL] = (bf16)acc[j];
}

// ---------------------------------------------------------------------------
// Fold 2 via MFMA: for each h, C_h[2048 d][32 r] = Wo_h[2048x128] @ Wup^T.
// ---------------------------------------------------------------------------
__global__ __launch_bounds__(256) void fold_o_k(
    const bf16* __restrict__ Wob, const float* __restrict__ Wup,
    bf16* __restrict__ WoEffT) {
  __shared__ __align__(16) bf16 As_[128 * 128];   // 32 KB
  __shared__ __align__(16) bf16 Bs_[32 * 128];    //  8 KB
  const int t = threadIdx.x, wave = t >> 6, lane = t & 63;
  const int quad = lane >> 4, lc = lane & 15;
  const int d0 = blockIdx.x * 128, h = blockIdx.y;
#pragma unroll
  for (int a = 0; a < 8; ++a) {
    int r0 = wave * 32 + a * 4;
    int row = r0 + (lane >> 4);
    int g = (lane & 15) ^ (row & 15);
    async_load16(Wob + (size_t)(d0 + row) * 2048 + h * 128 + g * 8,
                 As_ + r0 * 128);
  }
  {
    int row = t >> 3;                 // 0..31
    int c0 = (t & 7) * 2;             // chunk pair
    const float* src = Wup + row * 128 + c0 * 8;
    float4 f0 = ((const float4*)src)[0], f1 = ((const float4*)src)[1];
    float4 f2 = ((const float4*)src)[2], f3 = ((const float4*)src)[3];
    bf16x8 b0, b1;
    b0[0] = (bf16)f0.x; b0[1] = (bf16)f0.y; b0[2] = (bf16)f0.z; b0[3] = (bf16)f0.w;
    b0[4] = (bf16)f1.x; b0[5] = (bf16)f1.y; b0[6] = (bf16)f1.z; b0[7] = (bf16)f1.w;
    b1[0] = (bf16)f2.x; b1[1] = (bf16)f2.y; b1[2] = (bf16)f2.z; b1[3] = (bf16)f2.w;
    b1[4] = (bf16)f3.x; b1[5] = (bf16)f3.y; b1[6] = (bf16)f3.z; b1[7] = (bf16)f3.w;
    *(bf16x8*)(Bs_ + row * 128 + ((c0 ^ (row & 15)) * 8)) = b0;
    *(bf16x8*)(Bs_ + row * 128 + (((c0 + 1) ^ (row & 15)) * 8)) = b1;
  }
  __syncthreads();
  f32x4 acc[2][2] = {};
  const int wm = wave * 32;
#pragma unroll
  for (int kc = 0; kc < 4; ++kc) {
    bf16x8 af[2], bfr[2];
#pragma unroll
    for (int mi = 0; mi < 2; ++mi) {
      int m = wm + mi * 16 + lc;
      af[mi] = *(const bf16x8*)(As_ + m * 128 + (((kc * 4 + quad) ^ (m & 15)) * 8));
    }
#pragma unroll
    for (int ni = 0; ni < 2; ++ni) {
      int n = ni * 16 + lc;
      bfr[ni] = *(const bf16x8*)(Bs_ + n * 128 + (((kc * 4 + quad) ^ (n & 15)) * 8));
    }
#pragma unroll
    for (int mi = 0; mi < 2; ++mi)
#pragma unroll
      for (int ni = 0; ni < 2; ++ni)
        acc[mi][ni] = __builtin_amdgcn_mfma_f32_16x16x32_bf16(
            af[mi], bfr[ni], acc[mi][ni], 0, 0, 0);
  }
#pragma unroll
  for (int mi = 0; mi < 2; ++mi)
#pragma unroll
    for (int ni = 0; ni < 2; ++ni)
#pragma unroll
      for (int reg = 0; reg < 4; ++reg)
        WoEffT[(size_t)(d0 + wm + mi * 16 + quad * 4 + reg) * 512 + h * 32 +
               ni * 16 + lc] = (bf16)acc[mi][ni][reg];
}

// ---------------------------------------------------------------------------
// GEMM  C = A @ Bt^T.  A[M×K], Bt[N×K] bf16, fp32 accum. Tile 128×128, 4
// waves each 64×64 (4×4 frags), BK=64, double-buffered, one barrier/iter.
// 128B LDS rows (8 x16B slots), src-col swizzle g = slot ^ (row&7).
// EPI==1 (QKV producer):
//   mat 0 (Q): scaled by QSCALE*log2e (attn uses exp2).
//   mat 2 (V): stored TRANSPOSED per bh, tiled [16 kt][32 r][128 k] with
//              16B-chunk swizzle chunk' = chunk ^ (r&15) — exactly the linear
//              LDS image attn_k wants, so attn stages V via global_load_lds
//              with zero VALU work. The 4 acc regs are 4 consecutive k inside
//              one swizzle chunk (quad*4-aligned) -> ONE aligned bf16x4 store.
// ---------------------------------------------------------------------------
template <int EPI>
__global__ __launch_bounds__(256) void gemm_bt_k(
    const bf16* __restrict__ A, const bf16* __restrict__ Bt,
    void* __restrict__ Cv, int M, int N, int K) {
  __shared__ __align__(16) bf16 As[2][128 * 64];   // 32 KB
  __shared__ __align__(16) bf16 Bs[2][128 * 64];   // 32 KB
  const int t = threadIdx.x, wave = t >> 6, lane = t & 63;
  const int quad = lane >> 4, lc = lane & 15;
  const size_t m0 = (size_t)blockIdx.x * 128;
  const size_t n0 = (size_t)blockIdx.y * 128;
  const int wm = (wave >> 1) * 64, wn = (wave & 1) * 64;
  const int sr = lane >> 3, ss = lane & 7;
  const bf16* Aga[4]; const bf16* Bga[4]; int Loff[4];
#pragma unroll
  for (int a = 0; a < 4; ++a) {
    int row = wave * 32 + a * 8 + sr;
    Aga[a] = A + (m0 + row) * (size_t)K + (ss ^ (row & 7)) * 8;
    Bga[a] = Bt + (n0 + row) * (size_t)K + (ss ^ (row & 7)) * 8;
    Loff[a] = (wave * 32 + a * 8) * 64;
  }
  f32x4 acc[4][4] = {};
  const int NIT = K >> 6;
#pragma unroll
  for (int a = 0; a < 4; ++a) {
    async_load16(Aga[a], &As[0][Loff[a]]);
    async_load16(Bga[a], &Bs[0][Loff[a]]);
  }
  __syncthreads();
  for (int it = 0; it < NIT; ++it) {
    const int cur = it & 1;
    if (it + 1 < NIT) {
      const int k0 = (it + 1) * 64;
#pragma unroll
      for (int a = 0; a < 4; ++a) {
        async_load16(Aga[a] + k0, &As[1 - cur][Loff[a]]);
        async_load16(Bga[a] + k0, &Bs[1 - cur][Loff[a]]);
      }
    }
    const bf16* Asb = As[cur];
    const bf16* Bsb = Bs[cur];
#pragma unroll
    for (int kc = 0; kc < 2; ++kc) {
      bf16x8 af[4], bfr[4];
#pragma unroll
      for (int mi = 0; mi < 4; ++mi) {
        int m = wm + mi * 16 + lc;
        af[mi] = *(const bf16x8*)(Asb + m * 64 + (((kc * 4 + quad) ^ (m & 7)) * 8));
      }
#pragma unroll
      for (int ni = 0; ni < 4; ++ni) {
        int n = wn + ni * 16 + lc;
        bfr[ni] = *(const bf16x8*)(Bsb + n * 64 + (((kc * 4 + quad) ^ (n & 7)) * 8));
      }
#pragma unroll
      for (int mi = 0; mi < 4; ++mi)
#pragma unroll
        for (int ni = 0; ni < 4; ++ni)
          acc[mi][ni] = __builtin_amdgcn_mfma_f32_16x16x32_bf16(
              af[mi], bfr[ni], acc[mi][ni], 0, 0, 0);
    }
    __syncthreads();
  }

  if (EPI == 0) {
    float* C = (float*)Cv;
#pragma unroll
    for (int mi = 0; mi < 4; ++mi)
#pragma unroll
      for (int ni = 0; ni < 4; ++ni) {
        size_t row = m0 + wm + mi * 16 + quad * 4;
        size_t col = n0 + wn + ni * 16 + lc;
#pragma unroll
        for (int reg = 0; reg < 4; ++reg)
          C[(row + reg) * (size_t)N + col] = acc[mi][ni][reg];
      }
  } else {
    bf16* C = (bf16*)Cv;
#pragma unroll
    for (int mi = 0; mi < 4; ++mi)
#pragma unroll
      for (int ni = 0; ni < 4; ++ni) {
        int n = (int)n0 + wn + ni * 16 + lc;
        int mat = n >> 9, hh = (n >> 5) & 15, r = n & 31;
        float sc = (mat == 0) ? QSCALE_L2E : 1.0f;
        int trow = (int)m0 + wm + mi * 16 + quad * 4;   // multiple of 4
        int b = trow >> 11, tl = trow & 2047;
        if (mat == 2) {
          // 4 regs = 4 consecutive k in one swizzle chunk -> one 8B store
          int tile = tl >> 7, kin = tl & 127;           // kin % 4 == 0
          size_t off = ((size_t)(b * 16 + hh) * 3 + 2) * 65536 +
                       (size_t)tile * 4096 + r * 128 +
                       (((kin >> 3) ^ (r & 15)) << 3) + (kin & 7);
          bf16x4 pk;
#pragma unroll
          for (int reg = 0; reg < 4; ++reg) pk[reg] = (bf16)acc[mi][ni][reg];
          *(bf16x4*)(C + off) = pk;
        } else {
#pragma unroll
          for (int reg = 0; reg < 4; ++reg) {
            size_t off = (((size_t)(b * 16 + hh) * 3 + mat) * 2048 + tl + reg) * 32 + r;
            C[off] = (bf16)(acc[mi][ni][reg] * sc);
          }
        }
      }
  }
}

// ---------------------------------------------------------------------------
// Flash attention in rank space (no max-tracking). S computed TRANSPOSED:
// S^T = mfma(a=K_frag, b=Q_frag) so each lane's 4 acc regs are 4 consecutive
// k at fixed q, packing P into ONE ds_write_b64 per (u,tile).
// V arrives pre-transposed+tiled+swizzled from the producer -> staged straight
// into LDS via global_load_lds (no per-thread transpose, no LDS writes).
// Row sums via MFMA against a ones vector (lands in the same acc layout as O:
// os[reg] is exactly the row this lane stores -> no shuffles, and numerator/
// denominator use the same bf16-rounded P). Raw v_exp_f32 with pre-folded
// log2e scale (1 transcendental per element, no library fixup, no mul).
// grid (32 bh, 16 qb) = 512 blocks = exactly 2/CU.
// ---------------------------------------------------------------------------
__global__ __launch_bounds__(256) void attn_k(const bf16* __restrict__ QKVr,
                                              bf16* __restrict__ Yr) {
  const int bh = blockIdx.x, qb = blockIdx.y;
  const size_t base = (size_t)bh * 3 * 2048 * 32;
  const bf16* Q  = QKVr + base;
  const bf16* Kr = Q + 2048 * 32;
  const bf16* Vr = Kr + 2048 * 32;                 // [16 kt][32 r][128 k] swizzled
  __shared__ __align__(16) bf16 Ks[2][128 * 32];   // 16 KB
  __shared__ __align__(16) bf16 Vt[2][32 * 128];   // 16 KB
  __shared__ __align__(16) bf16 Ps[4 * 32 * 128];  // 32 KB
  const int t = threadIdx.x, wave = t >> 6, lane = t & 63;
  const int quad = lane >> 4, lc = lane & 15;
  const int qbase = qb * 128 + wave * 32;
  const bf16x8 qf0 = *(const bf16x8*)(Q + (size_t)(qbase + lc) * 32 + quad * 8);
  const bf16x8 qf1 = *(const bf16x8*)(Q + (size_t)(qbase + 16 + lc) * 32 + quad * 8);
  f32x4 o00 = {}, o01 = {}, o10 = {}, o11 = {};
  f32x4 os0 = {}, os1 = {};
  bf16x8 ones;
#pragma unroll
  for (int j = 0; j < 8; ++j) ones[j] = (bf16)1.0f;
  const int krow = wave * 16 + (lane >> 2);
  const bf16* Kg = Kr + (size_t)krow * 32 + ((lane & 3) ^ ((krow >> 1) & 3)) * 8;
  bf16* pw = Ps + wave * 32 * 128;

  // prologue: stage tile 0 (K rows + V^T image, both via async DMA)
  async_load16(Kg, &Ks[0][wave * 16 * 32]);
  async_load16(Kg + (size_t)64 * 32, &Ks[0][(64 + wave * 16) * 32]);
  async_load16(Vr + (wave * 2) * 512 + lane * 8, &Vt[0][(wave * 2) * 512]);
  async_load16(Vr + (wave * 2 + 1) * 512 + lane * 8, &Vt[0][(wave * 2 + 1) * 512]);
  __syncthreads();

  for (int it = 0; it < 16; ++it) {
    const int kt = it * 128, cur = it & 1;
    if (it < 15) {
      async_load16(Kg + (size_t)(kt + 128) * 32, &Ks[1 - cur][wave * 16 * 32]);
      async_load16(Kg + (size_t)(kt + 192) * 32, &Ks[1 - cur][(64 + wave * 16) * 32]);
      const bf16* vg = Vr + (size_t)(it + 1) * 4096;
      async_load16(vg + (wave * 2) * 512 + lane * 8, &Vt[1 - cur][(wave * 2) * 512]);
      async_load16(vg + (wave * 2 + 1) * 512 + lane * 8, &Vt[1 - cur][(wave * 2 + 1) * 512]);
    }
    const bf16* ksb = Ks[cur];
    // --- S^T = K Q^T per 16-key tile; exp2; pack; one b64 write per (u,tile) ---
#pragma unroll
    for (int ni = 0; ni < 8; ++ni) {
      int n = ni * 16 + lc;
      bf16x8 kf = *(const bf16x8*)(ksb + n * 32 + ((quad ^ ((n >> 1) & 3)) * 8));
      f32x4 z = {0.f, 0.f, 0.f, 0.f};
      f32x4 s0 = __builtin_amdgcn_mfma_f32_16x16x32_bf16(kf, qf0, z, 0, 0, 0);
      f32x4 s1 = __builtin_amdgcn_mfma_f32_16x16x32_bf16(kf, qf1, z, 0, 0, 0);
      bf16x4 p0, p1;
#pragma unroll
      for (int reg = 0; reg < 4; ++reg) {
        p0[reg] = (bf16)fast_exp2(s0[reg]);
        p1[reg] = (bf16)fast_exp2(s1[reg]);
      }
      int off = (((2 * ni + (quad >> 1)) ^ lc) * 8) + (quad & 1) * 4;
      *(bf16x4*)(pw + lc * 128 + off) = p0;
      *(bf16x4*)(pw + (16 + lc) * 128 + off) = p1;
    }
    // --- O += P V ; row-sums += P * ones (same acc layout as O) ---
    const bf16* vtb = Vt[cur];
#pragma unroll
    for (int kc = 0; kc < 4; ++kc) {
      int co = ((kc * 4 + quad) ^ lc) * 8;
      bf16x8 pf0 = *(const bf16x8*)(pw + lc * 128 + co);
      bf16x8 pf1 = *(const bf16x8*)(pw + (16 + lc) * 128 + co);
      bf16x8 v0 = *(const bf16x8*)(vtb + lc * 128 + co);
      bf16x8 v1 = *(const bf16x8*)(vtb + (16 + lc) * 128 + co);
      o00 = __builtin_amdgcn_mfma_f32_16x16x32_bf16(pf0, v0, o00, 0, 0, 0);
      o01 = __builtin_amdgcn_mfma_f32_16x16x32_bf16(pf0, v1, o01, 0, 0, 0);
      o10 = __builtin_amdgcn_mfma_f32_16x16x32_bf16(pf1, v0, o10, 0, 0, 0);
      o11 = __builtin_amdgcn_mfma_f32_16x16x32_bf16(pf1, v1, o11, 0, 0, 0);
      os0 = __builtin_amdgcn_mfma_f32_16x16x32_bf16(pf0, ones, os0, 0, 0, 0);
      os1 = __builtin_amdgcn_mfma_f32_16x16x32_bf16(pf1, ones, os1, 0, 0, 0);
    }
    __syncthreads();
  }
  // --- normalize & store: os[reg] is the sum for exactly this lane's row ---
  const int b = bh >> 4, h = bh & 15;
#pragma unroll
  for (int reg = 0; reg < 4; ++reg) {
    float i0 = 1.0f / os0[reg];
    float i1 = 1.0f / os1[reg];
    size_t r0 = (size_t)b * 2048 + qbase + quad * 4 + reg;
    size_t r1 = r0 + 16;
    Yr[r0 * 512 + h * 32 + lc]      = (bf16)(o00[reg] * i0);
    Yr[r0 * 512 + h * 32 + 16 + lc] = (bf16)(o01[reg] * i0);
    Yr[r1 * 512 + h * 32 + lc]      = (bf16)(o10[reg] * i1);
    Yr[r1 * 512 + h * 32 + 16 + lc] = (bf16)(o11[reg] * i1);
  }
}

// ---------------------------------------------------------------------------
extern "C" void kernel_launch(void* const* d_in, const int* in_sizes, int n_in,
                              void* d_out, int out_size, void* d_ws, size_t ws_size,
                              hipStream_t stream) {
  const float* x     = (const float*)d_in[0];
  const float* Wq    = (const float*)d_in[1];
  const float* Wk    = (const float*)d_in[2];
  const float* Wv    = (const float*)d_in[3];
  const float* Wo    = (const float*)d_in[4];
  const float* Wdown = (const float*)d_in[5];
  const float* Wup   = (const float*)d_in[6];
  float* out = (float*)d_out;

  char* ws = (char*)d_ws;
  bf16* EffT   = (bf16*)(ws);                 // [1536][2048]       6,291,456 B
  bf16* WoEffT = (bf16*)(ws + 6291456);       // [2048][512]        2,097,152 B
  bf16* QKVr   = (bf16*)(ws + 8388608);       // [32][3][2048][32] 12,582,912 B
  bf16* Wob    = (bf16*)(ws + 8388608);       // [2048][2048] — dead before QKVr written
  bf16* Yrb    = (bf16*)(ws + 20971520);      // [4096][512]        4,194,304 B
  bf16* xb     = (bf16*)(ws + 25165824);      // [4096][2048]      16,777,216 B

  cvt_k<<<dim3(4096), dim3(256), 0, stream>>>(x, xb);
  cvt_k<<<dim3(2048), dim3(256), 0, stream>>>(Wo, Wob);
  fold_qkv_k<<<dim3(48, 16), dim3(256), 0, stream>>>(Wq, Wk, Wv, Wdown, EffT);
  fold_o_k<<<dim3(16, 16), dim3(256), 0, stream>>>(Wob, Wup, WoEffT);
  gemm_bt_k<1><<<dim3(32, 12), dim3(256), 0, stream>>>(xb, EffT, QKVr,
                                                       4096, 1536, 2048);
  attn_k<<<dim3(32, 16), dim3(256), 0, stream>>>(QKVr, Yrb);
  gemm_bt_k<0><<<dim3(32, 16), dim3(256), 0, stream>>>(Yrb, WoEffT, out,
                                                       4096, 2048, 512);
}

// Round 3
// 241.057 us; speedup vs baseline: 1.1024x; 1.0316x over previous
//
#include <hip/hip_runtime.h>
#include <cstdint>
#include <cstddef>

typedef __bf16 bf16;
typedef __attribute__((ext_vector_type(8))) __bf16 bf16x8;
typedef __attribute__((ext_vector_type(4))) __bf16 bf16x4;
typedef __attribute__((ext_vector_type(2))) __bf16 bf16x2;
typedef __attribute__((ext_vector_type(4))) float f32x4;
typedef unsigned int u32;

#define D_MODEL 2048
#define QSCALE      0.17677669529663687f                      // 1/sqrt(32)
#define QSCALE_L2E  (0.17677669529663687f * 1.4426950408889634f)  // fold log2(e): exp(x)=exp2(x*l2e)

// async global->LDS, 16B per lane. LDS dest is wave-uniform base + lane*16.
__device__ inline void async_load16(const void* gp, void* lp) {
  __builtin_amdgcn_global_load_lds(
      (const __attribute__((address_space(1))) u32*)gp,
      (__attribute__((address_space(3))) u32*)lp, 16, 0, 0);
}

// Raw v_exp_f32 (2^x) — single transcendental, no library range fixup.
__device__ inline float fast_exp2(float x) {
#if __has_builtin(__builtin_amdgcn_exp2f)
  return __builtin_amdgcn_exp2f(x);
#else
  return __expf(x * 0.6931471805599453f);
#endif
}

// ---------------------------------------------------------------------------
// Convert fp32 -> bf16, 8 elements/thread (exact-multiple grids only).
// ---------------------------------------------------------------------------
__global__ __launch_bounds__(256) void cvt_k(const float* __restrict__ x,
                                             bf16* __restrict__ xb) {
  const int i = (blockIdx.x * 256 + threadIdx.x) * 8;
  float4 a = *(const float4*)(x + i);
  float4 b = *(const float4*)(x + i + 4);
  bf16x8 o;
  o[0] = (bf16)a.x; o[1] = (bf16)a.y; o[2] = (bf16)a.z; o[3] = (bf16)a.w;
  o[4] = (bf16)b.x; o[5] = (bf16)b.y; o[6] = (bf16)b.z; o[7] = (bf16)b.w;
  *(bf16x8*)(xb + i) = o;
}

// ---------------------------------------------------------------------------
// Fold 1: EffT[(mat*16+h)*32 + r][d] = sum_dh W[h*128+dh][d] * Wdown[dh][r]
// ---------------------------------------------------------------------------
__global__ __launch_bounds__(256) void fold_qkv_k(
    const float* __restrict__ Wq, const float* __restrict__ Wk,
    const float* __restrict__ Wv, const float* __restrict__ Wdown,
    bf16* __restrict__ EffT) {
  __shared__ float wd[128][32];
  const int t = threadIdx.x;
  for (int i = t; i < 128 * 32; i += 256)
    ((float*)wd)[i] = Wdown[i];
  __syncthreads();
  const int mh = blockIdx.x;                         // mat*16 + h
  const float* W = (mh < 16) ? Wq : ((mh < 32) ? Wk : Wv);
  const int hrow = (mh & 15) * 128;
  const int d = blockIdx.y * 128 + (t & 127);
  const int rh = (t >> 7) * 16;                      // wave-uniform: 0 or 16
  float acc[16];
#pragma unroll
  for (int j = 0; j < 16; ++j) acc[j] = 0.f;
#pragma unroll 4
  for (int k = 0; k < 128; ++k) {
    float w = W[(size_t)(hrow + k) * D_MODEL + d];
    const float* wr = &wd[k][rh];                    // broadcast ds reads
#pragma unroll
    for (int j = 0; j < 16; ++j) acc[j] += w * wr[j];
  }
  bf16* outp = EffT + (size_t)(mh * 32 + rh) * D_MODEL + d;
#pragma unroll
  for (int j = 0; j < 16; ++j) outp[(size_t)j * D_MODEL] = (bf16)acc[j];
}

// ---------------------------------------------------------------------------
// Fold 2 via MFMA: for each h, C_h[2048 d][32 r] = Wo_h[2048x128] @ Wup^T.
// ---------------------------------------------------------------------------
__global__ __launch_bounds__(256) void fold_o_k(
    const bf16* __restrict__ Wob, const float* __restrict__ Wup,
    bf16* __restrict__ WoEffT) {
  __shared__ __align__(16) bf16 As_[128 * 128];   // 32 KB
  __shared__ __align__(16) bf16 Bs_[32 * 128];    //  8 KB
  const int t = threadIdx.x, wave = t >> 6, lane = t & 63;
  const int quad = lane >> 4, lc = lane & 15;
  const int d0 = blockIdx.x * 128, h = blockIdx.y;
#pragma unroll
  for (int a = 0; a < 8; ++a) {
    int r0 = wave * 32 + a * 4;
    int row = r0 + (lane >> 4);
    int g = (lane & 15) ^ (row & 15);
    async_load16(Wob + (size_t)(d0 + row) * 2048 + h * 128 + g * 8,
                 As_ + r0 * 128);
  }
  {
    int row = t >> 3;                 // 0..31
    int c0 = (t & 7) * 2;             // chunk pair
    const float* src = Wup + row * 128 + c0 * 8;
    float4 f0 = ((const float4*)src)[0], f1 = ((const float4*)src)[1];
    float4 f2 = ((const float4*)src)[2], f3 = ((const float4*)src)[3];
    bf16x8 b0, b1;
    b0[0] = (bf16)f0.x; b0[1] = (bf16)f0.y; b0[2] = (bf16)f0.z; b0[3] = (bf16)f0.w;
    b0[4] = (bf16)f1.x; b0[5] = (bf16)f1.y; b0[6] = (bf16)f1.z; b0[7] = (bf16)f1.w;
    b1[0] = (bf16)f2.x; b1[1] = (bf16)f2.y; b1[2] = (bf16)f2.z; b1[3] = (bf16)f2.w;
    b1[4] = (bf16)f3.x; b1[5] = (bf16)f3.y; b1[6] = (bf16)f3.z; b1[7] = (bf16)f3.w;
    *(bf16x8*)(Bs_ + row * 128 + ((c0 ^ (row & 15)) * 8)) = b0;
    *(bf16x8*)(Bs_ + row * 128 + (((c0 + 1) ^ (row & 15)) * 8)) = b1;
  }
  __syncthreads();
  f32x4 acc[2][2] = {};
  const int wm = wave * 32;
#pragma unroll
  for (int kc = 0; kc < 4; ++kc) {
    bf16x8 af[2], bfr[2];
#pragma unroll
    for (int mi = 0; mi < 2; ++mi) {
      int m = wm + mi * 16 + lc;
      af[mi] = *(const bf16x8*)(As_ + m * 128 + (((kc * 4 + quad) ^ (m & 15)) * 8));
    }
#pragma unroll
    for (int ni = 0; ni < 2; ++ni) {
      int n = ni * 16 + lc;
      bfr[ni] = *(const bf16x8*)(Bs_ + n * 128 + (((kc * 4 + quad) ^ (n & 15)) * 8));
    }
#pragma unroll
    for (int mi = 0; mi < 2; ++mi)
#pragma unroll
      for (int ni = 0; ni < 2; ++ni)
        acc[mi][ni] = __builtin_amdgcn_mfma_f32_16x16x32_bf16(
            af[mi], bfr[ni], acc[mi][ni], 0, 0, 0);
  }
#pragma unroll
  for (int mi = 0; mi < 2; ++mi)
#pragma unroll
    for (int ni = 0; ni < 2; ++ni)
#pragma unroll
      for (int reg = 0; reg < 4; ++reg)
        WoEffT[(size_t)(d0 + wm + mi * 16 + quad * 4 + reg) * 512 + h * 32 +
               ni * 16 + lc] = (bf16)acc[mi][ni][reg];
}

// ---------------------------------------------------------------------------
// GEMM  C = A @ Bt^T.  A[M×K], Bt[N×K] bf16, fp32 accum. Tile BM×128, 4
// waves each (BM/2)×64 (MIx4 frags), BK=64, double-buffered, one barrier/iter.
// BM=128: LDS 64KB, 2 blocks/CU.  BM=64: LDS 48KB, 3 blocks/CU (use when the
// tile grid is 3/CU-shaped for load balance).
// EPI==1 (QKV producer): Q scaled by QSCALE*log2e; V stored transposed+tiled+
// swizzled ([16 kt][32 r][128 k], chunk' = chunk ^ (r&15)) so attn can stage
// it via global_load_lds directly. 4 acc regs = 4 consecutive k in one chunk
// -> ONE aligned bf16x4 store.
// ---------------------------------------------------------------------------
template <int EPI, int BM>
__global__ __launch_bounds__(256, (BM == 64 ? 3 : 2)) void gemm_bt_k(
    const bf16* __restrict__ A, const bf16* __restrict__ Bt,
    void* __restrict__ Cv, int M, int N, int K) {
  constexpr int MI = BM / 32;        // A-frags per wave (4 or 2)
  constexpr int AR = BM / 4;         // A rows staged per wave (32 or 16)
  __shared__ __align__(16) bf16 As[2][BM * 64];
  __shared__ __align__(16) bf16 Bs[2][128 * 64];
  const int t = threadIdx.x, wave = t >> 6, lane = t & 63;
  const int quad = lane >> 4, lc = lane & 15;
  const size_t m0 = (size_t)blockIdx.x * BM;
  const size_t n0 = (size_t)blockIdx.y * 128;
  const int wm = (wave >> 1) * (MI * 16), wn = (wave & 1) * 64;
  const int sr = lane >> 3, ss = lane & 7;
  const bf16* Aga[MI]; const bf16* Bga[4]; int LoffA[MI], LoffB[4];
#pragma unroll
  for (int a = 0; a < MI; ++a) {
    int row = wave * AR + a * 8 + sr;
    Aga[a] = A + (m0 + row) * (size_t)K + (ss ^ (row & 7)) * 8;
    LoffA[a] = (wave * AR + a * 8) * 64;
  }
#pragma unroll
  for (int a = 0; a < 4; ++a) {
    int row = wave * 32 + a * 8 + sr;
    Bga[a] = Bt + (n0 + row) * (size_t)K + (ss ^ (row & 7)) * 8;
    LoffB[a] = (wave * 32 + a * 8) * 64;
  }
  f32x4 acc[MI][4] = {};
  const int NIT = K >> 6;
#pragma unroll
  for (int a = 0; a < MI; ++a) async_load16(Aga[a], &As[0][LoffA[a]]);
#pragma unroll
  for (int a = 0; a < 4; ++a) async_load16(Bga[a], &Bs[0][LoffB[a]]);
  __syncthreads();
  for (int it = 0; it < NIT; ++it) {
    const int cur = it & 1;
    if (it + 1 < NIT) {
      const int k0 = (it + 1) * 64;
#pragma unroll
      for (int a = 0; a < MI; ++a) async_load16(Aga[a] + k0, &As[1 - cur][LoffA[a]]);
#pragma unroll
      for (int a = 0; a < 4; ++a) async_load16(Bga[a] + k0, &Bs[1 - cur][LoffB[a]]);
    }
    const bf16* Asb = As[cur];
    const bf16* Bsb = Bs[cur];
#pragma unroll
    for (int kc = 0; kc < 2; ++kc) {
      bf16x8 af[MI], bfr[4];
#pragma unroll
      for (int mi = 0; mi < MI; ++mi) {
        int m = wm + mi * 16 + lc;
        af[mi] = *(const bf16x8*)(Asb + m * 64 + (((kc * 4 + quad) ^ (m & 7)) * 8));
      }
#pragma unroll
      for (int ni = 0; ni < 4; ++ni) {
        int n = wn + ni * 16 + lc;
        bfr[ni] = *(const bf16x8*)(Bsb + n * 64 + (((kc * 4 + quad) ^ (n & 7)) * 8));
      }
#pragma unroll
      for (int mi = 0; mi < MI; ++mi)
#pragma unroll
        for (int ni = 0; ni < 4; ++ni)
          acc[mi][ni] = __builtin_amdgcn_mfma_f32_16x16x32_bf16(
              af[mi], bfr[ni], acc[mi][ni], 0, 0, 0);
    }
    __syncthreads();
  }

  if (EPI == 0) {
    float* C = (float*)Cv;
#pragma unroll
    for (int mi = 0; mi < MI; ++mi)
#pragma unroll
      for (int ni = 0; ni < 4; ++ni) {
        size_t row = m0 + wm + mi * 16 + quad * 4;
        size_t col = n0 + wn + ni * 16 + lc;
#pragma unroll
        for (int reg = 0; reg < 4; ++reg)
          C[(row + reg) * (size_t)N + col] = acc[mi][ni][reg];
      }
  } else {
    bf16* C = (bf16*)Cv;
#pragma unroll
    for (int mi = 0; mi < MI; ++mi)
#pragma unroll
      for (int ni = 0; ni < 4; ++ni) {
        int n = (int)n0 + wn + ni * 16 + lc;
        int mat = n >> 9, hh = (n >> 5) & 15, r = n & 31;
        float sc = (mat == 0) ? QSCALE_L2E : 1.0f;
        int trow = (int)m0 + wm + mi * 16 + quad * 4;   // multiple of 4
        int b = trow >> 11, tl = trow & 2047;
        if (mat == 2) {
          int tile = tl >> 7, kin = tl & 127;           // kin % 4 == 0
          size_t off = ((size_t)(b * 16 + hh) * 3 + 2) * 65536 +
                       (size_t)tile * 4096 + r * 128 +
                       (((kin >> 3) ^ (r & 15)) << 3) + (kin & 7);
          bf16x4 pk;
#pragma unroll
          for (int reg = 0; reg < 4; ++reg) pk[reg] = (bf16)acc[mi][ni][reg];
          *(bf16x4*)(C + off) = pk;
        } else {
#pragma unroll
          for (int reg = 0; reg < 4; ++reg) {
            size_t off = (((size_t)(b * 16 + hh) * 3 + mat) * 2048 + tl + reg) * 32 + r;
            C[off] = (bf16)(acc[mi][ni][reg] * sc);
          }
        }
      }
  }
}

// ---------------------------------------------------------------------------
// Flash attention in rank space, KV-SPLIT ×2 (flash-decoding): each block does
// 1024 keys, emitting UNNORMALIZED fp32 partial O + partial row-sums; comb_k
// normalizes. Grid (32 bh, 16 qb, 2 kv) = 1024 blocks = 4/CU; LDS = exactly
// 40KB (Ks 16 + Vt 16 + Ps 8) -> 4 blocks/CU, 4 waves/SIMD (2x latency
// hiding vs. the 64KB/2-block version).
// P is processed in 32-key QUARTERS: Ps per wave = 32q x 32k (2KB). Swizzle
// chunk' = chunk ^ (lc&3) ^ (lc>>2) keeps both b64 writes and b128 reads at
// the conflict-free floor. Row sums via MFMA-with-ones (same acc layout as O).
// ---------------------------------------------------------------------------
__global__ __launch_bounds__(256, 4) void attn_k(const bf16* __restrict__ QKVr,
                                                 float* __restrict__ Op,
                                                 float* __restrict__ Sums) {
  const int bh = blockIdx.x, qb = blockIdx.y, kvh = blockIdx.z;
  const size_t base = (size_t)bh * 3 * 65536;
  const bf16* Q   = QKVr + base;
  const bf16* Kr  = Q + 65536 + (size_t)kvh * 1024 * 32;
  const bf16* Vrb = Q + 131072 + (size_t)kvh * 8 * 4096;  // 8 tiles of [32r][128k]
  __shared__ __align__(16) bf16 Ks[2][128 * 32];   // 16 KB
  __shared__ __align__(16) bf16 Vt[2][32 * 128];   // 16 KB
  __shared__ __align__(16) bf16 Ps[4 * 32 * 32];   //  8 KB
  const int t = threadIdx.x, wave = t >> 6, lane = t & 63;
  const int quad = lane >> 4, lc = lane & 15;
  const int qbase = qb * 128 + wave * 32;
  const bf16x8 qf0 = *(const bf16x8*)(Q + (size_t)(qbase + lc) * 32 + quad * 8);
  const bf16x8 qf1 = *(const bf16x8*)(Q + (size_t)(qbase + 16 + lc) * 32 + quad * 8);
  f32x4 o00 = {}, o01 = {}, o10 = {}, o11 = {};
  f32x4 os0 = {}, os1 = {};
  bf16x8 ones;
#pragma unroll
  for (int j = 0; j < 8; ++j) ones[j] = (bf16)1.0f;
  const int krow = wave * 16 + (lane >> 2);
  const bf16* Kg = Kr + (size_t)krow * 32 + ((lane & 3) ^ ((krow >> 1) & 3)) * 8;
  bf16* pw = Ps + wave * 32 * 32;
  const int psw = (lc & 3) ^ (lc >> 2);            // per-lane P chunk swizzle

  // prologue: stage tile 0 (K rows + V^T image, both via async DMA)
  async_load16(Kg, &Ks[0][wave * 16 * 32]);
  async_load16(Kg + (size_t)64 * 32, &Ks[0][(64 + wave * 16) * 32]);
  async_load16(Vrb + (wave * 2) * 512 + lane * 8, &Vt[0][(wave * 2) * 512]);
  async_load16(Vrb + (wave * 2 + 1) * 512 + lane * 8, &Vt[0][(wave * 2 + 1) * 512]);
  __syncthreads();

  for (int it = 0; it < 8; ++it) {
    const int kt = it * 128, cur = it & 1;
    if (it < 7) {
      async_load16(Kg + (size_t)(kt + 128) * 32, &Ks[1 - cur][wave * 16 * 32]);
      async_load16(Kg + (size_t)(kt + 192) * 32, &Ks[1 - cur][(64 + wave * 16) * 32]);
      const bf16* vg = Vrb + (size_t)(it + 1) * 4096;
      async_load16(vg + (wave * 2) * 512 + lane * 8, &Vt[1 - cur][(wave * 2) * 512]);
      async_load16(vg + (wave * 2 + 1) * 512 + lane * 8, &Vt[1 - cur][(wave * 2 + 1) * 512]);
    }
    const bf16* ksb = Ks[cur];
    const bf16* vtb = Vt[cur];
#pragma unroll
    for (int qtr = 0; qtr < 4; ++qtr) {
      // --- S^T for 2x16 keys; exp2; pack into per-wave 32q x 32k Ps ---
#pragma unroll
      for (int nii = 0; nii < 2; ++nii) {
        int ni = qtr * 2 + nii;
        int n = ni * 16 + lc;
        bf16x8 kf = *(const bf16x8*)(ksb + n * 32 + ((quad ^ ((n >> 1) & 3)) * 8));
        f32x4 z = {0.f, 0.f, 0.f, 0.f};
        f32x4 s0 = __builtin_amdgcn_mfma_f32_16x16x32_bf16(kf, qf0, z, 0, 0, 0);
        f32x4 s1 = __builtin_amdgcn_mfma_f32_16x16x32_bf16(kf, qf1, z, 0, 0, 0);
        bf16x4 p0, p1;
#pragma unroll
        for (int reg = 0; reg < 4; ++reg) {
          p0[reg] = (bf16)fast_exp2(s0[reg]);
          p1[reg] = (bf16)fast_exp2(s1[reg]);
        }
        int off = (((2 * nii + (quad >> 1)) ^ psw) * 8) + (quad & 1) * 4;
        *(bf16x4*)(pw + lc * 32 + off) = p0;
        *(bf16x4*)(pw + (16 + lc) * 32 + off) = p1;
      }
      // --- O += P V ; row-sums += P * ones for this 32-key quarter ---
      int co = (quad ^ psw) * 8;
      bf16x8 pf0 = *(const bf16x8*)(pw + lc * 32 + co);
      bf16x8 pf1 = *(const bf16x8*)(pw + (16 + lc) * 32 + co);
      int vo = ((qtr * 4 + quad) ^ lc) * 8;
      bf16x8 v0 = *(const bf16x8*)(vtb + lc * 128 + vo);
      bf16x8 v1 = *(const bf16x8*)(vtb + (16 + lc) * 128 + vo);
      o00 = __builtin_amdgcn_mfma_f32_16x16x32_bf16(pf0, v0, o00, 0, 0, 0);
      o01 = __builtin_amdgcn_mfma_f32_16x16x32_bf16(pf0, v1, o01, 0, 0, 0);
      o10 = __builtin_amdgcn_mfma_f32_16x16x32_bf16(pf1, v0, o10, 0, 0, 0);
      o11 = __builtin_amdgcn_mfma_f32_16x16x32_bf16(pf1, v1, o11, 0, 0, 0);
      os0 = __builtin_amdgcn_mfma_f32_16x16x32_bf16(pf0, ones, os0, 0, 0, 0);
      os1 = __builtin_amdgcn_mfma_f32_16x16x32_bf16(pf1, ones, os1, 0, 0, 0);
    }
    __syncthreads();
  }
  // --- write unnormalized fp32 partials + per-row partial sums ---
  const int b = bh >> 4, h = bh & 15;
  float* op = Op + (size_t)kvh * 4096 * 512;
#pragma unroll
  for (int reg = 0; reg < 4; ++reg) {
    size_t r0 = (size_t)b * 2048 + qbase + quad * 4 + reg;
    size_t r1 = r0 + 16;
    op[r0 * 512 + h * 32 + lc]      = o00[reg];
    op[r0 * 512 + h * 32 + 16 + lc] = o01[reg];
    op[r1 * 512 + h * 32 + lc]      = o10[reg];
    op[r1 * 512 + h * 32 + 16 + lc] = o11[reg];
  }
  if (lc == 0) {
    float* sp = Sums + (size_t)kvh * 65536 + (size_t)bh * 2048 + qbase;
#pragma unroll
    for (int reg = 0; reg < 4; ++reg) {
      sp[quad * 4 + reg]      = os0[reg];
      sp[16 + quad * 4 + reg] = os1[reg];
    }
  }
}

// ---------------------------------------------------------------------------
// Combine: Yr[row][col] = (O0 + O1) / (s0 + s1), bf16 out. 8 cols/thread.
// ---------------------------------------------------------------------------
__global__ __launch_bounds__(256) void comb_k(const float* __restrict__ Op,
                                              const float* __restrict__ Sums,
                                              bf16* __restrict__ Yr) {
  const int idx = blockIdx.x * 256 + threadIdx.x;  // 262144 total
  const int row = idx >> 6;                        // 0..4095
  const int c8 = (idx & 63) * 8;                   // col base (one h per thread)
  const int b = row >> 11, tl = row & 2047;
  const int h = c8 >> 5;
  const size_t si = (size_t)(b * 16 + h) * 2048 + tl;
  const float inv = 1.0f / (Sums[si] + Sums[65536 + si]);
  const float4* p0 = (const float4*)(Op + (size_t)row * 512 + c8);
  const float4* p1 = (const float4*)(Op + 4096 * 512 + (size_t)row * 512 + c8);
  float4 a0 = p0[0], a1 = p0[1];
  float4 b0 = p1[0], b1 = p1[1];
  bf16x8 o;
  o[0] = (bf16)((a0.x + b0.x) * inv); o[1] = (bf16)((a0.y + b0.y) * inv);
  o[2] = (bf16)((a0.z + b0.z) * inv); o[3] = (bf16)((a0.w + b0.w) * inv);
  o[4] = (bf16)((a1.x + b1.x) * inv); o[5] = (bf16)((a1.y + b1.y) * inv);
  o[6] = (bf16)((a1.z + b1.z) * inv); o[7] = (bf16)((a1.w + b1.w) * inv);
  *(bf16x8*)(Yr + (size_t)row * 512 + c8) = o;
}

// ---------------------------------------------------------------------------
extern "C" void kernel_launch(void* const* d_in, const int* in_sizes, int n_in,
                              void* d_out, int out_size, void* d_ws, size_t ws_size,
                              hipStream_t stream) {
  const float* x     = (const float*)d_in[0];
  const float* Wq    = (const float*)d_in[1];
  const float* Wk    = (const float*)d_in[2];
  const float* Wv    = (const float*)d_in[3];
  const float* Wo    = (const float*)d_in[4];
  const float* Wdown = (const float*)d_in[5];
  const float* Wup   = (const float*)d_in[6];
  float* out = (float*)d_out;

  char* ws = (char*)d_ws;
  bf16*  EffT   = (bf16*)(ws);                // [1536][2048]       6,291,456 B
  float* Sums   = (float*)(ws);               // [2][32][2048] — EffT dead after gemm<1>
  bf16*  WoEffT = (bf16*)(ws + 6291456);      // [2048][512]        2,097,152 B
  bf16*  QKVr   = (bf16*)(ws + 8388608);      // [32][3][2048][32] 12,582,912 B
  bf16*  Wob    = (bf16*)(ws + 8388608);      // [2048][2048] — dead before QKVr written
  bf16*  Yrb    = (bf16*)(ws + 20971520);     // [4096][512]        4,194,304 B
  bf16*  xb     = (bf16*)(ws + 25165824);     // [4096][2048]      16,777,216 B
  float* Opart  = (float*)(ws + 25165824);    // [2][4096][512] f32 — xb dead after gemm<1>

  cvt_k<<<dim3(4096), dim3(256), 0, stream>>>(x, xb);
  cvt_k<<<dim3(2048), dim3(256), 0, stream>>>(Wo, Wob);
  fold_qkv_k<<<dim3(48, 16), dim3(256), 0, stream>>>(Wq, Wk, Wv, Wdown, EffT);
  fold_o_k<<<dim3(16, 16), dim3(256), 0, stream>>>(Wob, Wup, WoEffT);
  gemm_bt_k<1, 64><<<dim3(64, 12), dim3(256), 0, stream>>>(xb, EffT, QKVr,
                                                           4096, 1536, 2048);
  attn_k<<<dim3(32, 16, 2), dim3(256), 0, stream>>>(QKVr, Opart, Sums);
  comb_k<<<dim3(1024), dim3(256), 0, stream>>>(Opart, Sums, Yrb);
  gemm_bt_k<0, 128><<<dim3(32, 16), dim3(256), 0, stream>>>(Yrb, WoEffT, out,
                                                            4096, 2048, 512);
}

// Round 4
// 230.930 us; speedup vs baseline: 1.1508x; 1.0439x over previous
//
#include <hip/hip_runtime.h>
#include <cstdint>
#include <cstddef>

typedef __bf16 bf16;
typedef __attribute__((ext_vector_type(8))) __bf16 bf16x8;
typedef __attribute__((ext_vector_type(4))) __bf16 bf16x4;
typedef __attribute__((ext_vector_type(2))) __bf16 bf16x2;
typedef __attribute__((ext_vector_type(4))) float f32x4;
typedef unsigned int u32;

#define D_MODEL 2048
#define QSCALE      0.17677669529663687f                      // 1/sqrt(32)
#define QSCALE_L2E  (0.17677669529663687f * 1.4426950408889634f)  // fold log2(e): exp(x)=exp2(x*l2e)

// async global->LDS, 16B per lane. LDS dest is wave-uniform base + lane*16.
__device__ inline void async_load16(const void* gp, void* lp) {
  __builtin_amdgcn_global_load_lds(
      (const __attribute__((address_space(1))) u32*)gp,
      (__attribute__((address_space(3))) u32*)lp, 16, 0, 0);
}

// Raw v_exp_f32 (2^x) — single transcendental, no library range fixup.
__device__ inline float fast_exp2(float x) {
#if __has_builtin(__builtin_amdgcn_exp2f)
  return __builtin_amdgcn_exp2f(x);
#else
  return __expf(x * 0.6931471805599453f);
#endif
}

// ---------------------------------------------------------------------------
// prep_k: fused front-end. All four jobs depend only on kernel inputs, so one
// launch replaces four (cvt(x), cvt(Wo)+fold_o, fold_qkv) — kills 3 dispatch
// gaps and overlaps HBM-streaming cvt blocks with issue-bound fold blocks.
//   blocks [0,4096):    cvt x fp32 -> xb bf16 (8 elem/thread)
//   blocks [4096,4864): fold_qkv  EffT[(mat*16+h)*32+r][d] = W^T fold Wdown
//   blocks [4864,5120): fold_o    WoEffT[d][h*32+r] = Wo_h @ Wup^T via MFMA,
//                       reading Wo fp32 directly (reg cvt -> swizzled LDS).
// ---------------------------------------------------------------------------
__global__ __launch_bounds__(256) void prep_k(
    const float* __restrict__ x,  const float* __restrict__ Wq,
    const float* __restrict__ Wk, const float* __restrict__ Wv,
    const float* __restrict__ Wo, const float* __restrict__ Wdown,
    const float* __restrict__ Wup,
    bf16* __restrict__ xb, bf16* __restrict__ EffT,
    bf16* __restrict__ WoEffT) {
  __shared__ __align__(16) char smem_[40960];   // 40 KB: max of the branches
  const int bid = blockIdx.x;
  const int t = threadIdx.x;

  if (bid < 4096) {
    // ---- cvt x -> xb ----
    const int i = (bid * 256 + t) * 8;
    float4 a = *(const float4*)(x + i);
    float4 b = *(const float4*)(x + i + 4);
    bf16x8 o;
    o[0] = (bf16)a.x; o[1] = (bf16)a.y; o[2] = (bf16)a.z; o[3] = (bf16)a.w;
    o[4] = (bf16)b.x; o[5] = (bf16)b.y; o[6] = (bf16)b.z; o[7] = (bf16)b.w;
    *(bf16x8*)(xb + i) = o;
    return;
  }

  if (bid < 4864) {
    // ---- fold_qkv ----
    float* wd = (float*)smem_;                       // [128][32] = 16 KB
    for (int i = t; i < 128 * 32; i += 256) wd[i] = Wdown[i];
    __syncthreads();
    const int rel = bid - 4096;
    const int mh = rel % 48;                         // mat*16 + h
    const int dblk = rel / 48;
    const float* W = (mh < 16) ? Wq : ((mh < 32) ? Wk : Wv);
    const int hrow = (mh & 15) * 128;
    const int d = dblk * 128 + (t & 127);
    const int rh = (t >> 7) * 16;                    // wave-uniform: 0 or 16
    float acc[16];
#pragma unroll
    for (int j = 0; j < 16; ++j) acc[j] = 0.f;
#pragma unroll 4
    for (int k = 0; k < 128; ++k) {
      float w = W[(size_t)(hrow + k) * D_MODEL + d];
      const float* wr = wd + k * 32 + rh;            // broadcast ds reads
#pragma unroll
      for (int j = 0; j < 16; ++j) acc[j] += w * wr[j];
    }
    bf16* outp = EffT + (size_t)(mh * 32 + rh) * D_MODEL + d;
#pragma unroll
    for (int j = 0; j < 16; ++j) outp[(size_t)j * D_MODEL] = (bf16)acc[j];
    return;
  }

  // ---- fold_o via MFMA: C_h[128 d][32 r] = Wo_h[128x128] @ Wup^T ----
  bf16* As_ = (bf16*)smem_;              // 128*128 bf16 = 32 KB
  bf16* Bs_ = (bf16*)(smem_ + 32768);    //  32*128 bf16 =  8 KB
  const int rel = bid - 4864;
  const int d0 = (rel & 15) * 128, h = rel >> 4;
  const int wave = t >> 6, lane = t & 63;
  const int quad = lane >> 4, lc = lane & 15;
  // stage A from fp32 Wo (8 chunks of 8 elems per thread), swizzled write
#pragma unroll
  for (int a = 0; a < 8; ++a) {
    int cc = a * 256 + t;                // 0..2047
    int row = cc >> 4, c = cc & 15;
    const float* src = Wo + (size_t)(d0 + row) * 2048 + h * 128 + c * 8;
    float4 f0 = ((const float4*)src)[0], f1 = ((const float4*)src)[1];
    bf16x8 v;
    v[0] = (bf16)f0.x; v[1] = (bf16)f0.y; v[2] = (bf16)f0.z; v[3] = (bf16)f0.w;
    v[4] = (bf16)f1.x; v[5] = (bf16)f1.y; v[6] = (bf16)f1.z; v[7] = (bf16)f1.w;
    *(bf16x8*)(As_ + row * 128 + ((c ^ (row & 15)) * 8)) = v;
  }
  {
    int row = t >> 3;                 // 0..31
    int c0 = (t & 7) * 2;             // chunk pair
    const float* src = Wup + row * 128 + c0 * 8;
    float4 f0 = ((const float4*)src)[0], f1 = ((const float4*)src)[1];
    float4 f2 = ((const float4*)src)[2], f3 = ((const float4*)src)[3];
    bf16x8 b0, b1;
    b0[0] = (bf16)f0.x; b0[1] = (bf16)f0.y; b0[2] = (bf16)f0.z; b0[3] = (bf16)f0.w;
    b0[4] = (bf16)f1.x; b0[5] = (bf16)f1.y; b0[6] = (bf16)f1.z; b0[7] = (bf16)f1.w;
    b1[0] = (bf16)f2.x; b1[1] = (bf16)f2.y; b1[2] = (bf16)f2.z; b1[3] = (bf16)f2.w;
    b1[4] = (bf16)f3.x; b1[5] = (bf16)f3.y; b1[6] = (bf16)f3.z; b1[7] = (bf16)f3.w;
    *(bf16x8*)(Bs_ + row * 128 + ((c0 ^ (row & 15)) * 8)) = b0;
    *(bf16x8*)(Bs_ + row * 128 + (((c0 + 1) ^ (row & 15)) * 8)) = b1;
  }
  __syncthreads();
  f32x4 acc[2][2] = {};
  const int wm = wave * 32;
#pragma unroll
  for (int kc = 0; kc < 4; ++kc) {
    bf16x8 af[2], bfr[2];
#pragma unroll
    for (int mi = 0; mi < 2; ++mi) {
      int m = wm + mi * 16 + lc;
      af[mi] = *(const bf16x8*)(As_ + m * 128 + (((kc * 4 + quad) ^ (m & 15)) * 8));
    }
#pragma unroll
    for (int ni = 0; ni < 2; ++ni) {
      int n = ni * 16 + lc;
      bfr[ni] = *(const bf16x8*)(Bs_ + n * 128 + (((kc * 4 + quad) ^ (n & 15)) * 8));
    }
#pragma unroll
    for (int mi = 0; mi < 2; ++mi)
#pragma unroll
      for (int ni = 0; ni < 2; ++ni)
        acc[mi][ni] = __builtin_amdgcn_mfma_f32_16x16x32_bf16(
            af[mi], bfr[ni], acc[mi][ni], 0, 0, 0);
  }
#pragma unroll
  for (int mi = 0; mi < 2; ++mi)
#pragma unroll
    for (int ni = 0; ni < 2; ++ni)
#pragma unroll
      for (int reg = 0; reg < 4; ++reg)
        WoEffT[(size_t)(d0 + wm + mi * 16 + quad * 4 + reg) * 512 + h * 32 +
               ni * 16 + lc] = (bf16)acc[mi][ni][reg];
}

// ---------------------------------------------------------------------------
// GEMM  C = A @ Bt^T.  A[M×K], Bt[N×K] bf16, fp32 accum. Tile BM×128, 4
// waves each (BM/2)×64 (MIx4 frags), BK=64, double-buffered, one barrier/iter.
// BM=128: LDS 64KB, 2 blocks/CU.  BM=64: LDS 48KB, 3 blocks/CU (use when the
// tile grid is 3/CU-shaped for load balance).
// EPI==1 (QKV producer): Q scaled by QSCALE*log2e; V stored transposed+tiled+
// swizzled ([16 kt][32 r][128 k], chunk' = chunk ^ (r&15)) so attn can stage
// it via global_load_lds directly. 4 acc regs = 4 consecutive k in one chunk
// -> ONE aligned bf16x4 store.
// ---------------------------------------------------------------------------
template <int EPI, int BM>
__global__ __launch_bounds__(256, (BM == 64 ? 3 : 2)) void gemm_bt_k(
    const bf16* __restrict__ A, const bf16* __restrict__ Bt,
    void* __restrict__ Cv, int M, int N, int K) {
  constexpr int MI = BM / 32;        // A-frags per wave (4 or 2)
  constexpr int AR = BM / 4;         // A rows staged per wave (32 or 16)
  __shared__ __align__(16) bf16 As[2][BM * 64];
  __shared__ __align__(16) bf16 Bs[2][128 * 64];
  const int t = threadIdx.x, wave = t >> 6, lane = t & 63;
  const int quad = lane >> 4, lc = lane & 15;
  const size_t m0 = (size_t)blockIdx.x * BM;
  const size_t n0 = (size_t)blockIdx.y * 128;
  const int wm = (wave >> 1) * (MI * 16), wn = (wave & 1) * 64;
  const int sr = lane >> 3, ss = lane & 7;
  const bf16* Aga[MI]; const bf16* Bga[4]; int LoffA[MI], LoffB[4];
#pragma unroll
  for (int a = 0; a < MI; ++a) {
    int row = wave * AR + a * 8 + sr;
    Aga[a] = A + (m0 + row) * (size_t)K + (ss ^ (row & 7)) * 8;
    LoffA[a] = (wave * AR + a * 8) * 64;
  }
#pragma unroll
  for (int a = 0; a < 4; ++a) {
    int row = wave * 32 + a * 8 + sr;
    Bga[a] = Bt + (n0 + row) * (size_t)K + (ss ^ (row & 7)) * 8;
    LoffB[a] = (wave * 32 + a * 8) * 64;
  }
  f32x4 acc[MI][4] = {};
  const int NIT = K >> 6;
#pragma unroll
  for (int a = 0; a < MI; ++a) async_load16(Aga[a], &As[0][LoffA[a]]);
#pragma unroll
  for (int a = 0; a < 4; ++a) async_load16(Bga[a], &Bs[0][LoffB[a]]);
  __syncthreads();
  for (int it = 0; it < NIT; ++it) {
    const int cur = it & 1;
    if (it + 1 < NIT) {
      const int k0 = (it + 1) * 64;
#pragma unroll
      for (int a = 0; a < MI; ++a) async_load16(Aga[a] + k0, &As[1 - cur][LoffA[a]]);
#pragma unroll
      for (int a = 0; a < 4; ++a) async_load16(Bga[a] + k0, &Bs[1 - cur][LoffB[a]]);
    }
    const bf16* Asb = As[cur];
    const bf16* Bsb = Bs[cur];
#pragma unroll
    for (int kc = 0; kc < 2; ++kc) {
      bf16x8 af[MI], bfr[4];
#pragma unroll
      for (int mi = 0; mi < MI; ++mi) {
        int m = wm + mi * 16 + lc;
        af[mi] = *(const bf16x8*)(Asb + m * 64 + (((kc * 4 + quad) ^ (m & 7)) * 8));
      }
#pragma unroll
      for (int ni = 0; ni < 4; ++ni) {
        int n = wn + ni * 16 + lc;
        bfr[ni] = *(const bf16x8*)(Bsb + n * 64 + (((kc * 4 + quad) ^ (n & 7)) * 8));
      }
#pragma unroll
      for (int mi = 0; mi < MI; ++mi)
#pragma unroll
        for (int ni = 0; ni < 4; ++ni)
          acc[mi][ni] = __builtin_amdgcn_mfma_f32_16x16x32_bf16(
              af[mi], bfr[ni], acc[mi][ni], 0, 0, 0);
    }
    __syncthreads();
  }

  if (EPI == 0) {
    float* C = (float*)Cv;
#pragma unroll
    for (int mi = 0; mi < MI; ++mi)
#pragma unroll
      for (int ni = 0; ni < 4; ++ni) {
        size_t row = m0 + wm + mi * 16 + quad * 4;
        size_t col = n0 + wn + ni * 16 + lc;
#pragma unroll
        for (int reg = 0; reg < 4; ++reg)
          C[(row + reg) * (size_t)N + col] = acc[mi][ni][reg];
      }
  } else {
    bf16* C = (bf16*)Cv;
#pragma unroll
    for (int mi = 0; mi < MI; ++mi)
#pragma unroll
      for (int ni = 0; ni < 4; ++ni) {
        int n = (int)n0 + wn + ni * 16 + lc;
        int mat = n >> 9, hh = (n >> 5) & 15, r = n & 31;
        float sc = (mat == 0) ? QSCALE_L2E : 1.0f;
        int trow = (int)m0 + wm + mi * 16 + quad * 4;   // multiple of 4
        int b = trow >> 11, tl = trow & 2047;
        if (mat == 2) {
          int tile = tl >> 7, kin = tl & 127;           // kin % 4 == 0
          size_t off = ((size_t)(b * 16 + hh) * 3 + 2) * 65536 +
                       (size_t)tile * 4096 + r * 128 +
                       (((kin >> 3) ^ (r & 15)) << 3) + (kin & 7);
          bf16x4 pk;
#pragma unroll
          for (int reg = 0; reg < 4; ++reg) pk[reg] = (bf16)acc[mi][ni][reg];
          *(bf16x4*)(C + off) = pk;
        } else {
#pragma unroll
          for (int reg = 0; reg < 4; ++reg) {
            size_t off = (((size_t)(b * 16 + hh) * 3 + mat) * 2048 + tl + reg) * 32 + r;
            C[off] = (bf16)(acc[mi][ni][reg] * sc);
          }
        }
      }
  }
}

// ---------------------------------------------------------------------------
// Flash attention in rank space, KV-SPLIT ×2 (flash-decoding): each block does
// 1024 keys, emitting UNNORMALIZED fp32 partial O + partial row-sums; comb_k
// normalizes. Grid (32 bh, 16 qb, 2 kv) = 1024 blocks = 4/CU; LDS = exactly
// 40KB (Ks 16 + Vt 16 + Ps 8) -> 4 blocks/CU, 4 waves/SIMD.
// P in 32-key QUARTERS: Ps per wave = 32q x 32k (2KB). Swizzle keeps b64
// writes and b128 reads conflict-free. Row sums via MFMA-with-ones.
// ---------------------------------------------------------------------------
__global__ __launch_bounds__(256, 4) void attn_k(const bf16* __restrict__ QKVr,
                                                 float* __restrict__ Op,
                                                 float* __restrict__ Sums) {
  const int bh = blockIdx.x, qb = blockIdx.y, kvh = blockIdx.z;
  const size_t base = (size_t)bh * 3 * 65536;
  const bf16* Q   = QKVr + base;
  const bf16* Kr  = Q + 65536 + (size_t)kvh * 1024 * 32;
  const bf16* Vrb = Q + 131072 + (size_t)kvh * 8 * 4096;  // 8 tiles of [32r][128k]
  __shared__ __align__(16) bf16 Ks[2][128 * 32];   // 16 KB
  __shared__ __align__(16) bf16 Vt[2][32 * 128];   // 16 KB
  __shared__ __align__(16) bf16 Ps[4 * 32 * 32];   //  8 KB
  const int t = threadIdx.x, wave = t >> 6, lane = t & 63;
  const int quad = lane >> 4, lc = lane & 15;
  const int qbase = qb * 128 + wave * 32;
  const bf16x8 qf0 = *(const bf16x8*)(Q + (size_t)(qbase + lc) * 32 + quad * 8);
  const bf16x8 qf1 = *(const bf16x8*)(Q + (size_t)(qbase + 16 + lc) * 32 + quad * 8);
  f32x4 o00 = {}, o01 = {}, o10 = {}, o11 = {};
  f32x4 os0 = {}, os1 = {};
  bf16x8 ones;
#pragma unroll
  for (int j = 0; j < 8; ++j) ones[j] = (bf16)1.0f;
  const int krow = wave * 16 + (lane >> 2);
  const bf16* Kg = Kr + (size_t)krow * 32 + ((lane & 3) ^ ((krow >> 1) & 3)) * 8;
  bf16* pw = Ps + wave * 32 * 32;
  const int psw = (lc & 3) ^ (lc >> 2);            // per-lane P chunk swizzle

  // prologue: stage tile 0 (K rows + V^T image, both via async DMA)
  async_load16(Kg, &Ks[0][wave * 16 * 32]);
  async_load16(Kg + (size_t)64 * 32, &Ks[0][(64 + wave * 16) * 32]);
  async_load16(Vrb + (wave * 2) * 512 + lane * 8, &Vt[0][(wave * 2) * 512]);
  async_load16(Vrb + (wave * 2 + 1) * 512 + lane * 8, &Vt[0][(wave * 2 + 1) * 512]);
  __syncthreads();

  for (int it = 0; it < 8; ++it) {
    const int kt = it * 128, cur = it & 1;
    if (it < 7) {
      async_load16(Kg + (size_t)(kt + 128) * 32, &Ks[1 - cur][wave * 16 * 32]);
      async_load16(Kg + (size_t)(kt + 192) * 32, &Ks[1 - cur][(64 + wave * 16) * 32]);
      const bf16* vg = Vrb + (size_t)(it + 1) * 4096;
      async_load16(vg + (wave * 2) * 512 + lane * 8, &Vt[1 - cur][(wave * 2) * 512]);
      async_load16(vg + (wave * 2 + 1) * 512 + lane * 8, &Vt[1 - cur][(wave * 2 + 1) * 512]);
    }
    const bf16* ksb = Ks[cur];
    const bf16* vtb = Vt[cur];
#pragma unroll
    for (int qtr = 0; qtr < 4; ++qtr) {
      // --- S^T for 2x16 keys; exp2; pack into per-wave 32q x 32k Ps ---
#pragma unroll
      for (int nii = 0; nii < 2; ++nii) {
        int ni = qtr * 2 + nii;
        int n = ni * 16 + lc;
        bf16x8 kf = *(const bf16x8*)(ksb + n * 32 + ((quad ^ ((n >> 1) & 3)) * 8));
        f32x4 z = {0.f, 0.f, 0.f, 0.f};
        f32x4 s0 = __builtin_amdgcn_mfma_f32_16x16x32_bf16(kf, qf0, z, 0, 0, 0);
        f32x4 s1 = __builtin_amdgcn_mfma_f32_16x16x32_bf16(kf, qf1, z, 0, 0, 0);
        bf16x4 p0, p1;
#pragma unroll
        for (int reg = 0; reg < 4; ++reg) {
          p0[reg] = (bf16)fast_exp2(s0[reg]);
          p1[reg] = (bf16)fast_exp2(s1[reg]);
        }
        int off = (((2 * nii + (quad >> 1)) ^ psw) * 8) + (quad & 1) * 4;
        *(bf16x4*)(pw + lc * 32 + off) = p0;
        *(bf16x4*)(pw + (16 + lc) * 32 + off) = p1;
      }
      // --- O += P V ; row-sums += P * ones for this 32-key quarter ---
      int co = (quad ^ psw) * 8;
      bf16x8 pf0 = *(const bf16x8*)(pw + lc * 32 + co);
      bf16x8 pf1 = *(const bf16x8*)(pw + (16 + lc) * 32 + co);
      int vo = ((qtr * 4 + quad) ^ lc) * 8;
      bf16x8 v0 = *(const bf16x8*)(vtb + lc * 128 + vo);
      bf16x8 v1 = *(const bf16x8*)(vtb + (16 + lc) * 128 + vo);
      o00 = __builtin_amdgcn_mfma_f32_16x16x32_bf16(pf0, v0, o00, 0, 0, 0);
      o01 = __builtin_amdgcn_mfma_f32_16x16x32_bf16(pf0, v1, o01, 0, 0, 0);
      o10 = __builtin_amdgcn_mfma_f32_16x16x32_bf16(pf1, v0, o10, 0, 0, 0);
      o11 = __builtin_amdgcn_mfma_f32_16x16x32_bf16(pf1, v1, o11, 0, 0, 0);
      os0 = __builtin_amdgcn_mfma_f32_16x16x32_bf16(pf0, ones, os0, 0, 0, 0);
      os1 = __builtin_amdgcn_mfma_f32_16x16x32_bf16(pf1, ones, os1, 0, 0, 0);
    }
    __syncthreads();
  }
  // --- write unnormalized fp32 partials + per-row partial sums ---
  const int b = bh >> 4, h = bh & 15;
  float* op = Op + (size_t)kvh * 4096 * 512;
#pragma unroll
  for (int reg = 0; reg < 4; ++reg) {
    size_t r0 = (size_t)b * 2048 + qbase + quad * 4 + reg;
    size_t r1 = r0 + 16;
    op[r0 * 512 + h * 32 + lc]      = o00[reg];
    op[r0 * 512 + h * 32 + 16 + lc] = o01[reg];
    op[r1 * 512 + h * 32 + lc]      = o10[reg];
    op[r1 * 512 + h * 32 + 16 + lc] = o11[reg];
  }
  if (lc == 0) {
    float* sp = Sums + (size_t)kvh * 65536 + (size_t)bh * 2048 + qbase;
#pragma unroll
    for (int reg = 0; reg < 4; ++reg) {
      sp[quad * 4 + reg]      = os0[reg];
      sp[16 + quad * 4 + reg] = os1[reg];
    }
  }
}

// ---------------------------------------------------------------------------
// Combine: Yr[row][col] = (O0 + O1) / (s0 + s1), bf16 out. 8 cols/thread.
// ---------------------------------------------------------------------------
__global__ __launch_bounds__(256) void comb_k(const float* __restrict__ Op,
                                              const float* __restrict__ Sums,
                                              bf16* __restrict__ Yr) {
  const int idx = blockIdx.x * 256 + threadIdx.x;  // 262144 total
  const int row = idx >> 6;                        // 0..4095
  const int c8 = (idx & 63) * 8;                   // col base (one h per thread)
  const int b = row >> 11, tl = row & 2047;
  const int h = c8 >> 5;
  const size_t si = (size_t)(b * 16 + h) * 2048 + tl;
  const float inv = 1.0f / (Sums[si] + Sums[65536 + si]);
  const float4* p0 = (const float4*)(Op + (size_t)row * 512 + c8);
  const float4* p1 = (const float4*)(Op + 4096 * 512 + (size_t)row * 512 + c8);
  float4 a0 = p0[0], a1 = p0[1];
  float4 b0 = p1[0], b1 = p1[1];
  bf16x8 o;
  o[0] = (bf16)((a0.x + b0.x) * inv); o[1] = (bf16)((a0.y + b0.y) * inv);
  o[2] = (bf16)((a0.z + b0.z) * inv); o[3] = (bf16)((a0.w + b0.w) * inv);
  o[4] = (bf16)((a1.x + b1.x) * inv); o[5] = (bf16)((a1.y + b1.y) * inv);
  o[6] = (bf16)((a1.z + b1.z) * inv); o[7] = (bf16)((a1.w + b1.w) * inv);
  *(bf16x8*)(Yr + (size_t)row * 512 + c8) = o;
}

// ---------------------------------------------------------------------------
extern "C" void kernel_launch(void* const* d_in, const int* in_sizes, int n_in,
                              void* d_out, int out_size, void* d_ws, size_t ws_size,
                              hipStream_t stream) {
  const float* x     = (const float*)d_in[0];
  const float* Wq    = (const float*)d_in[1];
  const float* Wk    = (const float*)d_in[2];
  const float* Wv    = (const float*)d_in[3];
  const float* Wo    = (const float*)d_in[4];
  const float* Wdown = (const float*)d_in[5];
  const float* Wup   = (const float*)d_in[6];
  float* out = (float*)d_out;

  char* ws = (char*)d_ws;
  bf16*  EffT   = (bf16*)(ws);                // [1536][2048]       6,291,456 B
  float* Sums   = (float*)(ws);               // [2][32][2048] — EffT dead after gemm<1>
  bf16*  WoEffT = (bf16*)(ws + 6291456);      // [2048][512]        2,097,152 B
  bf16*  QKVr   = (bf16*)(ws + 8388608);      // [32][3][2048][32] 12,582,912 B
  bf16*  Yrb    = (bf16*)(ws + 20971520);     // [4096][512]        4,194,304 B
  bf16*  xb     = (bf16*)(ws + 25165824);     // [4096][2048]      16,777,216 B
  float* Opart  = (float*)(ws + 25165824);    // [2][4096][512] f32 — xb dead after gemm<1>

  prep_k<<<dim3(5120), dim3(256), 0, stream>>>(x, Wq, Wk, Wv, Wo, Wdown, Wup,
                                               xb, EffT, WoEffT);
  gemm_bt_k<1, 64><<<dim3(64, 12), dim3(256), 0, stream>>>(xb, EffT, QKVr,
                                                           4096, 1536, 2048);
  attn_k<<<dim3(32, 16, 2), dim3(256), 0, stream>>>(QKVr, Opart, Sums);
  comb_k<<<dim3(1024), dim3(256), 0, stream>>>(Opart, Sums, Yrb);
  gemm_bt_k<0, 128><<<dim3(32, 16), dim3(256), 0, stream>>>(Yrb, WoEffT, out,
                                                            4096, 2048, 512);
}

// Round 6
// 224.364 us; speedup vs baseline: 1.1844x; 1.0293x over previous
//
#include <hip/hip_runtime.h>
#include <cstdint>
#include <cstddef>

typedef __bf16 bf16;
typedef __attribute__((ext_vector_type(8))) __bf16 bf16x8;
typedef __attribute__((ext_vector_type(4))) __bf16 bf16x4;
typedef __attribute__((ext_vector_type(2))) __bf16 bf16x2;
typedef __attribute__((ext_vector_type(4))) float f32x4;
typedef unsigned int u32;

#define D_MODEL 2048
#define QSCALE      0.17677669529663687f                      // 1/sqrt(32)
#define QSCALE_L2E  (0.17677669529663687f * 1.4426950408889634f)  // fold log2(e): exp(x)=exp2(x*l2e)

// async global->LDS, 16B per lane. LDS dest is wave-uniform base + lane*16.
__device__ inline void async_load16(const void* gp, void* lp) {
  __builtin_amdgcn_global_load_lds(
      (const __attribute__((address_space(1))) u32*)gp,
      (__attribute__((address_space(3))) u32*)lp, 16, 0, 0);
}

// Raw v_exp_f32 (2^x) — single transcendental, no library range fixup.
__device__ inline float fast_exp2(float x) {
#if __has_builtin(__builtin_amdgcn_exp2f)
  return __builtin_amdgcn_exp2f(x);
#else
  return __expf(x * 0.6931471805599453f);
#endif
}

// ---------------------------------------------------------------------------
// prep_k: fused front-end, one launch. Branch order puts the longest-latency
// blocks FIRST so streaming cvt blocks backfill their stalls:
//   blocks [0,768):     fold_qkv  EffT[(mat*16+h)*32+r][d] = W^T fold Wdown.
//                       Wdown read via the SCALAR pipe (rh is wave-uniform;
//                       readfirstlane -> s_load broadcast): no LDS, no
//                       ds_read on the critical path. W loads batched 8 deep.
//   blocks [768,1024):  fold_o via MFMA, reading Wo fp32 directly.
//   blocks [1024,2048): cvt x fp32 -> xb bf16, grid-stride 4 chunks/block.
// ---------------------------------------------------------------------------
__global__ __launch_bounds__(256) void prep_k(
    const float* __restrict__ x,  const float* __restrict__ Wq,
    const float* __restrict__ Wk, const float* __restrict__ Wv,
    const float* __restrict__ Wo, const float* __restrict__ Wdown,
    const float* __restrict__ Wup,
    bf16* __restrict__ xb, bf16* __restrict__ EffT,
    bf16* __restrict__ WoEffT) {
  __shared__ __align__(16) char smem_[40960];   // 40 KB (fold_o needs it all)
  const int bid = blockIdx.x;
  const int t = threadIdx.x;

  if (bid < 768) {
    // ---- fold_qkv ----
    const int mh = bid % 48;                         // mat*16 + h
    const int dblk = bid / 48;
    const float* W = (mh < 16) ? Wq : ((mh < 32) ? Wk : Wv);
    const int hrow = (mh & 15) * 128;
    const int d = dblk * 128 + (t & 127);
    const int rh = (t >> 7) * 16;                    // wave-uniform: 0 or 16
    const int rhs = __builtin_amdgcn_readfirstlane(rh);
    const float* wdn = Wdown + rhs;                  // scalar base -> s_load
    float acc[16];
#pragma unroll
    for (int j = 0; j < 16; ++j) acc[j] = 0.f;
    for (int kb = 0; kb < 16; ++kb) {                // 8 k per iteration
      float wv[8];
#pragma unroll
      for (int u = 0; u < 8; ++u)
        wv[u] = W[(size_t)(hrow + kb * 8 + u) * D_MODEL + d];
#pragma unroll
      for (int u = 0; u < 8; ++u) {
#pragma unroll
        for (int j = 0; j < 16; ++j)
          acc[j] += wv[u] * wdn[(kb * 8 + u) * 32 + j];   // SGPR operand
      }
    }
    bf16* outp = EffT + (size_t)(mh * 32 + rh) * D_MODEL + d;
#pragma unroll
    for (int j = 0; j < 16; ++j) outp[(size_t)j * D_MODEL] = (bf16)acc[j];
    return;
  }

  if (bid >= 1024) {
    // ---- cvt x -> xb: 4 chunks, 8 loads in flight ----
    const int tid = (bid - 1024) * 256 + t;          // 0..262143
    float4 v[8];
#pragma unroll
    for (int p = 0; p < 4; ++p) {
      const int i = (tid + p * 262144) * 8;
      v[2 * p]     = *(const float4*)(x + i);
      v[2 * p + 1] = *(const float4*)(x + i + 4);
    }
#pragma unroll
    for (int p = 0; p < 4; ++p) {
      const int i = (tid + p * 262144) * 8;
      bf16x8 o;
      o[0] = (bf16)v[2*p].x;   o[1] = (bf16)v[2*p].y;
      o[2] = (bf16)v[2*p].z;   o[3] = (bf16)v[2*p].w;
      o[4] = (bf16)v[2*p+1].x; o[5] = (bf16)v[2*p+1].y;
      o[6] = (bf16)v[2*p+1].z; o[7] = (bf16)v[2*p+1].w;
      *(bf16x8*)(xb + i) = o;
    }
    return;
  }

  // ---- fold_o via MFMA: C_h[128 d][32 r] = Wo_h[128x128] @ Wup^T ----
  bf16* As_ = (bf16*)smem_;              // 128*128 bf16 = 32 KB
  bf16* Bs_ = (bf16*)(smem_ + 32768);    //  32*128 bf16 =  8 KB
  const int rel = bid - 768;
  const int d0 = (rel & 15) * 128, h = rel >> 4;
  const int wave = t >> 6, lane = t & 63;
  const int quad = lane >> 4, lc = lane & 15;
  // stage A from fp32 Wo (8 chunks of 8 elems per thread), swizzled write
#pragma unroll
  for (int a = 0; a < 8; ++a) {
    int cc = a * 256 + t;                // 0..2047
    int row = cc >> 4, c = cc & 15;
    const float* src = Wo + (size_t)(d0 + row) * 2048 + h * 128 + c * 8;
    float4 f0 = ((const float4*)src)[0], f1 = ((const float4*)src)[1];
    bf16x8 v;
    v[0] = (bf16)f0.x; v[1] = (bf16)f0.y; v[2] = (bf16)f0.z; v[3] = (bf16)f0.w;
    v[4] = (bf16)f1.x; v[5] = (bf16)f1.y; v[6] = (bf16)f1.z; v[7] = (bf16)f1.w;
    *(bf16x8*)(As_ + row * 128 + ((c ^ (row & 15)) * 8)) = v;
  }
  {
    int row = t >> 3;                 // 0..31
    int c0 = (t & 7) * 2;             // chunk pair
    const float* src = Wup + row * 128 + c0 * 8;
    float4 f0 = ((const float4*)src)[0], f1 = ((const float4*)src)[1];
    float4 f2 = ((const float4*)src)[2], f3 = ((const float4*)src)[3];
    bf16x8 b0, b1;
    b0[0] = (bf16)f0.x; b0[1] = (bf16)f0.y; b0[2] = (bf16)f0.z; b0[3] = (bf16)f0.w;
    b0[4] = (bf16)f1.x; b0[5] = (bf16)f1.y; b0[6] = (bf16)f1.z; b0[7] = (bf16)f1.w;
    b1[0] = (bf16)f2.x; b1[1] = (bf16)f2.y; b1[2] = (bf16)f2.z; b1[3] = (bf16)f2.w;
    b1[4] = (bf16)f3.x; b1[5] = (bf16)f3.y; b1[6] = (bf16)f3.z; b1[7] = (bf16)f3.w;
    *(bf16x8*)(Bs_ + row * 128 + ((c0 ^ (row & 15)) * 8)) = b0;
    *(bf16x8*)(Bs_ + row * 128 + (((c0 + 1) ^ (row & 15)) * 8)) = b1;
  }
  __syncthreads();
  f32x4 acc[2][2] = {};
  const int wm = wave * 32;
#pragma unroll
  for (int kc = 0; kc < 4; ++kc) {
    bf16x8 af[2], bfr[2];
#pragma unroll
    for (int mi = 0; mi < 2; ++mi) {
      int m = wm + mi * 16 + lc;
      af[mi] = *(const bf16x8*)(As_ + m * 128 + (((kc * 4 + quad) ^ (m & 15)) * 8));
    }
#pragma unroll
    for (int ni = 0; ni < 2; ++ni) {
      int n = ni * 16 + lc;
      bfr[ni] = *(const bf16x8*)(Bs_ + n * 128 + (((kc * 4 + quad) ^ (n & 15)) * 8));
    }
#pragma unroll
    for (int mi = 0; mi < 2; ++mi)
#pragma unroll
      for (int ni = 0; ni < 2; ++ni)
        acc[mi][ni] = __builtin_amdgcn_mfma_f32_16x16x32_bf16(
            af[mi], bfr[ni], acc[mi][ni], 0, 0, 0);
  }
#pragma unroll
  for (int mi = 0; mi < 2; ++mi)
#pragma unroll
    for (int ni = 0; ni < 2; ++ni)
#pragma unroll
      for (int reg = 0; reg < 4; ++reg)
        WoEffT[(size_t)(d0 + wm + mi * 16 + quad * 4 + reg) * 512 + h * 32 +
               ni * 16 + lc] = (bf16)acc[mi][ni][reg];
}

// ---------------------------------------------------------------------------
// GEMM  C = A @ Bt^T.  A[M×K], Bt[N×K] bf16, fp32 accum. Tile BM×128, 4
// waves each (BM/2)×64 (MIx4 frags), BK=64, double-buffered, one barrier/iter.
// BM=128: LDS 64KB, 2 blocks/CU.  BM=64: LDS 48KB, 3 blocks/CU (use when the
// tile grid is 3/CU-shaped for load balance).
// EPI==1 (QKV producer): Q scaled by QSCALE*log2e; V stored transposed+tiled+
// swizzled ([16 kt][32 r][128 k], chunk' = chunk ^ (r&15)) so attn can stage
// it via global_load_lds directly. 4 acc regs = 4 consecutive k in one chunk
// -> ONE aligned bf16x4 store.
// ---------------------------------------------------------------------------
template <int EPI, int BM>
__global__ __launch_bounds__(256, (BM == 64 ? 3 : 2)) void gemm_bt_k(
    const bf16* __restrict__ A, const bf16* __restrict__ Bt,
    void* __restrict__ Cv, int M, int N, int K) {
  constexpr int MI = BM / 32;        // A-frags per wave (4 or 2)
  constexpr int AR = BM / 4;         // A rows staged per wave (32 or 16)
  __shared__ __align__(16) bf16 As[2][BM * 64];
  __shared__ __align__(16) bf16 Bs[2][128 * 64];
  const int t = threadIdx.x, wave = t >> 6, lane = t & 63;
  const int quad = lane >> 4, lc = lane & 15;
  const size_t m0 = (size_t)blockIdx.x * BM;
  const size_t n0 = (size_t)blockIdx.y * 128;
  const int wm = (wave >> 1) * (MI * 16), wn = (wave & 1) * 64;
  const int sr = lane >> 3, ss = lane & 7;
  const bf16* Aga[MI]; const bf16* Bga[4]; int LoffA[MI], LoffB[4];
#pragma unroll
  for (int a = 0; a < MI; ++a) {
    int row = wave * AR + a * 8 + sr;
    Aga[a] = A + (m0 + row) * (size_t)K + (ss ^ (row & 7)) * 8;
    LoffA[a] = (wave * AR + a * 8) * 64;
  }
#pragma unroll
  for (int a = 0; a < 4; ++a) {
    int row = wave * 32 + a * 8 + sr;
    Bga[a] = Bt + (n0 + row) * (size_t)K + (ss ^ (row & 7)) * 8;
    LoffB[a] = (wave * 32 + a * 8) * 64;
  }
  f32x4 acc[MI][4] = {};
  const int NIT = K >> 6;
#pragma unroll
  for (int a = 0; a < MI; ++a) async_load16(Aga[a], &As[0][LoffA[a]]);
#pragma unroll
  for (int a = 0; a < 4; ++a) async_load16(Bga[a], &Bs[0][LoffB[a]]);
  __syncthreads();
  for (int it = 0; it < NIT; ++it) {
    const int cur = it & 1;
    if (it + 1 < NIT) {
      const int k0 = (it + 1) * 64;
#pragma unroll
      for (int a = 0; a < MI; ++a) async_load16(Aga[a] + k0, &As[1 - cur][LoffA[a]]);
#pragma unroll
      for (int a = 0; a < 4; ++a) async_load16(Bga[a] + k0, &Bs[1 - cur][LoffB[a]]);
    }
    const bf16* Asb = As[cur];
    const bf16* Bsb = Bs[cur];
#pragma unroll
    for (int kc = 0; kc < 2; ++kc) {
      bf16x8 af[MI], bfr[4];
#pragma unroll
      for (int mi = 0; mi < MI; ++mi) {
        int m = wm + mi * 16 + lc;
        af[mi] = *(const bf16x8*)(Asb + m * 64 + (((kc * 4 + quad) ^ (m & 7)) * 8));
      }
#pragma unroll
      for (int ni = 0; ni < 4; ++ni) {
        int n = wn + ni * 16 + lc;
        bfr[ni] = *(const bf16x8*)(Bsb + n * 64 + (((kc * 4 + quad) ^ (n & 7)) * 8));
      }
#pragma unroll
      for (int mi = 0; mi < MI; ++mi)
#pragma unroll
        for (int ni = 0; ni < 4; ++ni)
          acc[mi][ni] = __builtin_amdgcn_mfma_f32_16x16x32_bf16(
              af[mi], bfr[ni], acc[mi][ni], 0, 0, 0);
    }
    __syncthreads();
  }

  if (EPI == 0) {
    float* C = (float*)Cv;
#pragma unroll
    for (int mi = 0; mi < MI; ++mi)
#pragma unroll
      for (int ni = 0; ni < 4; ++ni) {
        size_t row = m0 + wm + mi * 16 + quad * 4;
        size_t col = n0 + wn + ni * 16 + lc;
#pragma unroll
        for (int reg = 0; reg < 4; ++reg)
          C[(row + reg) * (size_t)N + col] = acc[mi][ni][reg];
      }
  } else {
    bf16* C = (bf16*)Cv;
#pragma unroll
    for (int mi = 0; mi < MI; ++mi)
#pragma unroll
      for (int ni = 0; ni < 4; ++ni) {
        int n = (int)n0 + wn + ni * 16 + lc;
        int mat = n >> 9, hh = (n >> 5) & 15, r = n & 31;
        float sc = (mat == 0) ? QSCALE_L2E : 1.0f;
        int trow = (int)m0 + wm + mi * 16 + quad * 4;   // multiple of 4
        int b = trow >> 11, tl = trow & 2047;
        if (mat == 2) {
          int tile = tl >> 7, kin = tl & 127;           // kin % 4 == 0
          size_t off = ((size_t)(b * 16 + hh) * 3 + 2) * 65536 +
                       (size_t)tile * 4096 + r * 128 +
                       (((kin >> 3) ^ (r & 15)) << 3) + (kin & 7);
          bf16x4 pk;
#pragma unroll
          for (int reg = 0; reg < 4; ++reg) pk[reg] = (bf16)acc[mi][ni][reg];
          *(bf16x4*)(C + off) = pk;
        } else {
#pragma unroll
          for (int reg = 0; reg < 4; ++reg) {
            size_t off = (((size_t)(b * 16 + hh) * 3 + mat) * 2048 + tl + reg) * 32 + r;
            C[off] = (bf16)(acc[mi][ni][reg] * sc);
          }
        }
      }
  }
}

// ---------------------------------------------------------------------------
// Flash attention in rank space, KV-SPLIT ×2 (flash-decoding): each block does
// 1024 keys, emitting UNNORMALIZED fp32 partial O + partial row-sums; comb_k
// normalizes. Grid (32 bh, 16 qb, 2 kv) = 1024 blocks = 4/CU; LDS = exactly
// 40KB (Ks 16 + Vt 16 + Ps 8) -> 4 blocks/CU, 4 waves/SIMD.
// P in 32-key QUARTERS: Ps per wave = 32q x 32k (2KB). Swizzle keeps b64
// writes and b128 reads conflict-free. Row sums via MFMA-with-ones.
// ---------------------------------------------------------------------------
__global__ __launch_bounds__(256, 4) void attn_k(const bf16* __restrict__ QKVr,
                                                 float* __restrict__ Op,
                                                 float* __restrict__ Sums) {
  const int bh = blockIdx.x, qb = blockIdx.y, kvh = blockIdx.z;
  const size_t base = (size_t)bh * 3 * 65536;
  const bf16* Q   = QKVr + base;
  const bf16* Kr  = Q + 65536 + (size_t)kvh * 1024 * 32;
  const bf16* Vrb = Q + 131072 + (size_t)kvh * 8 * 4096;  // 8 tiles of [32r][128k]
  __shared__ __align__(16) bf16 Ks[2][128 * 32];   // 16 KB
  __shared__ __align__(16) bf16 Vt[2][32 * 128];   // 16 KB
  __shared__ __align__(16) bf16 Ps[4 * 32 * 32];   //  8 KB
  const int t = threadIdx.x, wave = t >> 6, lane = t & 63;
  const int quad = lane >> 4, lc = lane & 15;
  const int qbase = qb * 128 + wave * 32;
  const bf16x8 qf0 = *(const bf16x8*)(Q + (size_t)(qbase + lc) * 32 + quad * 8);
  const bf16x8 qf1 = *(const bf16x8*)(Q + (size_t)(qbase + 16 + lc) * 32 + quad * 8);
  f32x4 o00 = {}, o01 = {}, o10 = {}, o11 = {};
  f32x4 os0 = {}, os1 = {};
  bf16x8 ones;
#pragma unroll
  for (int j = 0; j < 8; ++j) ones[j] = (bf16)1.0f;
  const int krow = wave * 16 + (lane >> 2);
  const bf16* Kg = Kr + (size_t)krow * 32 + ((lane & 3) ^ ((krow >> 1) & 3)) * 8;
  bf16* pw = Ps + wave * 32 * 32;
  const int psw = (lc & 3) ^ (lc >> 2);            // per-lane P chunk swizzle

  // prologue: stage tile 0 (K rows + V^T image, both via async DMA)
  async_load16(Kg, &Ks[0][wave * 16 * 32]);
  async_load16(Kg + (size_t)64 * 32, &Ks[0][(64 + wave * 16) * 32]);
  async_load16(Vrb + (wave * 2) * 512 + lane * 8, &Vt[0][(wave * 2) * 512]);
  async_load16(Vrb + (wave * 2 + 1) * 512 + lane * 8, &Vt[0][(wave * 2 + 1) * 512]);
  __syncthreads();

  for (int it = 0; it < 8; ++it) {
    const int kt = it * 128, cur = it & 1;
    if (it < 7) {
      async_load16(Kg + (size_t)(kt + 128) * 32, &Ks[1 - cur][wave * 16 * 32]);
      async_load16(Kg + (size_t)(kt + 192) * 32, &Ks[1 - cur][(64 + wave * 16) * 32]);
      const bf16* vg = Vrb + (size_t)(it + 1) * 4096;
      async_load16(vg + (wave * 2) * 512 + lane * 8, &Vt[1 - cur][(wave * 2) * 512]);
      async_load16(vg + (wave * 2 + 1) * 512 + lane * 8, &Vt[1 - cur][(wave * 2 + 1) * 512]);
    }
    const bf16* ksb = Ks[cur];
    const bf16* vtb = Vt[cur];
#pragma unroll
    for (int qtr = 0; qtr < 4; ++qtr) {
      // --- S^T for 2x16 keys; exp2; pack into per-wave 32q x 32k Ps ---
#pragma unroll
      for (int nii = 0; nii < 2; ++nii) {
        int ni = qtr * 2 + nii;
        int n = ni * 16 + lc;
        bf16x8 kf = *(const bf16x8*)(ksb + n * 32 + ((quad ^ ((n >> 1) & 3)) * 8));
        f32x4 z = {0.f, 0.f, 0.f, 0.f};
        f32x4 s0 = __builtin_amdgcn_mfma_f32_16x16x32_bf16(kf, qf0, z, 0, 0, 0);
        f32x4 s1 = __builtin_amdgcn_mfma_f32_16x16x32_bf16(kf, qf1, z, 0, 0, 0);
        bf16x4 p0, p1;
#pragma unroll
        for (int reg = 0; reg < 4; ++reg) {
          p0[reg] = (bf16)fast_exp2(s0[reg]);
          p1[reg] = (bf16)fast_exp2(s1[reg]);
        }
        int off = (((2 * nii + (quad >> 1)) ^ psw) * 8) + (quad & 1) * 4;
        *(bf16x4*)(pw + lc * 32 + off) = p0;
        *(bf16x4*)(pw + (16 + lc) * 32 + off) = p1;
      }
      // --- O += P V ; row-sums += P * ones for this 32-key quarter ---
      int co = (quad ^ psw) * 8;
      bf16x8 pf0 = *(const bf16x8*)(pw + lc * 32 + co);
      bf16x8 pf1 = *(const bf16x8*)(pw + (16 + lc) * 32 + co);
      int vo = ((qtr * 4 + quad) ^ lc) * 8;
      bf16x8 v0 = *(const bf16x8*)(vtb + lc * 128 + vo);
      bf16x8 v1 = *(const bf16x8*)(vtb + (16 + lc) * 128 + vo);
      o00 = __builtin_amdgcn_mfma_f32_16x16x32_bf16(pf0, v0, o00, 0, 0, 0);
      o01 = __builtin_amdgcn_mfma_f32_16x16x32_bf16(pf0, v1, o01, 0, 0, 0);
      o10 = __builtin_amdgcn_mfma_f32_16x16x32_bf16(pf1, v0, o10, 0, 0, 0);
      o11 = __builtin_amdgcn_mfma_f32_16x16x32_bf16(pf1, v1, o11, 0, 0, 0);
      os0 = __builtin_amdgcn_mfma_f32_16x16x32_bf16(pf0, ones, os0, 0, 0, 0);
      os1 = __builtin_amdgcn_mfma_f32_16x16x32_bf16(pf1, ones, os1, 0, 0, 0);
    }
    __syncthreads();
  }
  // --- write unnormalized fp32 partials + per-row partial sums ---
  const int b = bh >> 4, h = bh & 15;
  float* op = Op + (size_t)kvh * 4096 * 512;
#pragma unroll
  for (int reg = 0; reg < 4; ++reg) {
    size_t r0 = (size_t)b * 2048 + qbase + quad * 4 + reg;
    size_t r1 = r0 + 16;
    op[r0 * 512 + h * 32 + lc]      = o00[reg];
    op[r0 * 512 + h * 32 + 16 + lc] = o01[reg];
    op[r1 * 512 + h * 32 + lc]      = o10[reg];
    op[r1 * 512 + h * 32 + 16 + lc] = o11[reg];
  }
  if (lc == 0) {
    float* sp = Sums + (size_t)kvh * 65536 + (size_t)bh * 2048 + qbase;
#pragma unroll
    for (int reg = 0; reg < 4; ++reg) {
      sp[quad * 4 + reg]      = os0[reg];
      sp[16 + quad * 4 + reg] = os1[reg];
    }
  }
}

// ---------------------------------------------------------------------------
// Combine: Yr[row][col] = (O0 + O1) / (s0 + s1), bf16 out. 8 cols/thread.
// ---------------------------------------------------------------------------
__global__ __launch_bounds__(256) void comb_k(const float* __restrict__ Op,
                                              const float* __restrict__ Sums,
                                              bf16* __restrict__ Yr) {
  const int idx = blockIdx.x * 256 + threadIdx.x;  // 262144 total
  const int row = idx >> 6;                        // 0..4095
  const int c8 = (idx & 63) * 8;                   // col base (one h per thread)
  const int b = row >> 11, tl = row & 2047;
  const int h = c8 >> 5;
  const size_t si = (size_t)(b * 16 + h) * 2048 + tl;
  const float inv = 1.0f / (Sums[si] + Sums[65536 + si]);
  const float4* p0 = (const float4*)(Op + (size_t)row * 512 + c8);
  const float4* p1 = (const float4*)(Op + 4096 * 512 + (size_t)row * 512 + c8);
  float4 a0 = p0[0], a1 = p0[1];
  float4 b0 = p1[0], b1 = p1[1];
  bf16x8 o;
  o[0] = (bf16)((a0.x + b0.x) * inv); o[1] = (bf16)((a0.y + b0.y) * inv);
  o[2] = (bf16)((a0.z + b0.z) * inv); o[3] = (bf16)((a0.w + b0.w) * inv);
  o[4] = (bf16)((a1.x + b1.x) * inv); o[5] = (bf16)((a1.y + b1.y) * inv);
  o[6] = (bf16)((a1.z + b1.z) * inv); o[7] = (bf16)((a1.w + b1.w) * inv);
  *(bf16x8*)(Yr + (size_t)row * 512 + c8) = o;
}

// ---------------------------------------------------------------------------
extern "C" void kernel_launch(void* const* d_in, const int* in_sizes, int n_in,
                              void* d_out, int out_size, void* d_ws, size_t ws_size,
                              hipStream_t stream) {
  const float* x     = (const float*)d_in[0];
  const float* Wq    = (const float*)d_in[1];
  const float* Wk    = (const float*)d_in[2];
  const float* Wv    = (const float*)d_in[3];
  const float* Wo    = (const float*)d_in[4];
  const float* Wdown = (const float*)d_in[5];
  const float* Wup   = (const float*)d_in[6];
  float* out = (float*)d_out;

  char* ws = (char*)d_ws;
  bf16*  EffT   = (bf16*)(ws);                // [1536][2048]       6,291,456 B
  float* Sums   = (float*)(ws);               // [2][32][2048] — EffT dead after gemm<1>
  bf16*  WoEffT = (bf16*)(ws + 6291456);      // [2048][512]        2,097,152 B
  bf16*  QKVr   = (bf16*)(ws + 8388608);      // [32][3][2048][32] 12,582,912 B
  bf16*  Yrb    = (bf16*)(ws + 20971520);     // [4096][512]        4,194,304 B
  bf16*  xb     = (bf16*)(ws + 25165824);     // [4096][2048]      16,777,216 B
  float* Opart  = (float*)(ws + 25165824);    // [2][4096][512] f32 — xb dead after gemm<1>

  prep_k<<<dim3(2048), dim3(256), 0, stream>>>(x, Wq, Wk, Wv, Wo, Wdown, Wup,
                                               xb, EffT, WoEffT);
  gemm_bt_k<1, 64><<<dim3(64, 12), dim3(256), 0, stream>>>(xb, EffT, QKVr,
                                                           4096, 1536, 2048);
  attn_k<<<dim3(32, 16, 2), dim3(256), 0, stream>>>(QKVr, Opart, Sums);
  comb_k<<<dim3(1024), dim3(256), 0, stream>>>(Opart, Sums, Yrb);
  gemm_bt_k<0, 128><<<dim3(32, 16), dim3(256), 0, stream>>>(Yrb, WoEffT, out,
                                                            4096, 2048, 512);
}